// Round 5
// baseline (287.218 us; speedup 1.0000x reference)
//
#include <hip/hip_runtime.h>

#define BB 8
#define NN 2048
#define DD 768
#define KI 10
#define KR 5

typedef __attribute__((ext_vector_type(8))) short bf16x8;
typedef __attribute__((ext_vector_type(4))) float f32x4;

#define FENCE() asm volatile("" ::: "memory")
#define BARRIER() do { FENCE(); __builtin_amdgcn_s_barrier(); FENCE(); } while (0)
#define VMCNT0() asm volatile("s_waitcnt vmcnt(0)" ::: "memory")

__device__ __forceinline__ void async_copy16(void* ldsp, const void* g) {
  __builtin_amdgcn_global_load_lds(
      (const __attribute__((address_space(1))) unsigned int*)g,
      (__attribute__((address_space(3))) unsigned int*)ldsp, 16, 0, 0);
}

__device__ __forceinline__ unsigned short f2bf_rn(float x) {
  unsigned u = __float_as_uint(x);
  unsigned r = (u + 0x7fffu + ((u >> 16) & 1u)) >> 16;
  return (unsigned short)r;
}

// ---------------- split fp32 -> bf16 hi/lo ----------------
__global__ __launch_bounds__(256) void k_split(const float* __restrict__ q,
                                               const float* __restrict__ k,
                                               unsigned short* __restrict__ qh,
                                               unsigned short* __restrict__ ql,
                                               unsigned short* __restrict__ kh,
                                               unsigned short* __restrict__ kl) {
  const int n4 = BB * NN * DD / 4;
  const float4* src = (const float4*)(blockIdx.y ? k : q);
  ushort4* h = (ushort4*)(blockIdx.y ? kh : qh);
  ushort4* lo = (ushort4*)(blockIdx.y ? kl : ql);
  for (int i = blockIdx.x * blockDim.x + threadIdx.x; i < n4;
       i += gridDim.x * blockDim.x) {
    float4 v = src[i];
    ushort4 hv, lv;
    hv.x = f2bf_rn(v.x); lv.x = f2bf_rn(v.x - __uint_as_float((unsigned)hv.x << 16));
    hv.y = f2bf_rn(v.y); lv.y = f2bf_rn(v.y - __uint_as_float((unsigned)hv.y << 16));
    hv.z = f2bf_rn(v.z); lv.z = f2bf_rn(v.z - __uint_as_float((unsigned)hv.z << 16));
    hv.w = f2bf_rn(v.w); lv.w = f2bf_rn(v.w - __uint_as_float((unsigned)hv.w << 16));
    h[i] = hv; lo[i] = lv;
  }
}

// ---------------- 256x256-tile pipelined MFMA row-stats kernel ----------------
// 8 waves (2x4), BK=64, double-buffered 128KB LDS, XOR slot-swizzle,
// stage T+1 during T's phases 0-1, drain vmcnt(0) only at tile boundary.
__global__ __launch_bounds__(512, 2) void k_mfma8(const unsigned short* __restrict__ qh,
                                                  const unsigned short* __restrict__ ql,
                                                  const unsigned short* __restrict__ kh,
                                                  const unsigned short* __restrict__ kl,
                                                  float* __restrict__ pm,
                                                  float* __restrict__ pl,
                                                  float* __restrict__ sdiag) {
  extern __shared__ char lds[];
  const int flat = blockIdx.y * 64 + blockIdx.x;      // 0..511
  const int nid = (flat & 7) * 64 + (flat >> 3);      // chunked: one batch per XCD
  const int b = nid >> 6;
  const int tile = nid & 63;
  const int tm = tile >> 3, tn = tile & 7;
  const int tid = threadIdx.x;
  const int w = tid >> 6, lane = tid & 63;
  const int wr = w >> 2, wc = w & 3;
  const int l15 = lane & 15, g4 = lane >> 4;

  const size_t bOff = (size_t)b * NN * (DD * 2);
  const char* Aseg[3] = {(const char*)qh + bOff, (const char*)qh + bOff,
                         (const char*)ql + bOff};
  const char* Bseg[3] = {(const char*)kh + bOff, (const char*)kl + bOff,
                         (const char*)kh + bOff};

  // staging maps: LDS linear 1KB chunks -> inverse-swizzled global source
  int aSrc[4], bSrc[4], ldsOff[4];
#pragma unroll
  for (int e = 0; e < 4; e++) {
    const int chunk = e * 8 + w;                 // 0..31
    const int r = chunk * 8 + (lane >> 3);       // row 0..255 in tile
    const int sw = ((lane & 7) ^ (lane >> 3)) << 4;
    aSrc[e] = (tm * 256 + r) * 1536 + sw;
    bSrc[e] = (tn * 256 + r) * 1536 + sw;
    ldsOff[e] = chunk * 1024;                    // wave-uniform LDS dest
  }

  // fragment-read bases (swizzled slot lookup)
  const int rbA = (wr * 128 + l15) * 128;
  const int rbB = (wc * 64 + l15) * 128;
  int swk[2];
  swk[0] = (g4 ^ (lane & 7)) << 4;
  swk[1] = ((4 + g4) ^ (lane & 7)) << 4;

  f32x4 acc[8][4];
#pragma unroll
  for (int i = 0; i < 8; i++)
#pragma unroll
    for (int j = 0; j < 4; j++) acc[i][j] = (f32x4){0.f, 0.f, 0.f, 0.f};

  auto stageA = [&](int u, int buf) {
    const char* S = Aseg[u / 12] + (u % 12) * 128;
#pragma unroll
    for (int e = 0; e < 4; e++)
      async_copy16(lds + buf * 65536 + ldsOff[e], S + aSrc[e]);
  };
  auto stageB = [&](int u, int buf) {
    const char* S = Bseg[u / 12] + (u % 12) * 128;
#pragma unroll
    for (int e = 0; e < 4; e++)
      async_copy16(lds + buf * 65536 + 32768 + ldsOff[e], S + bSrc[e]);
  };

  // prologue: tile 0 into buf 0
  stageA(0, 0);
  stageB(0, 0);
  VMCNT0();
  BARRIER();

  bf16x8 af[4][2], bf01[2][2], bf23[2][2];

  for (int t = 0; t < 36; ++t) {
    const int cur = t & 1;
    const char* Ab = lds + cur * 65536;
    const char* Bb = Ab + 32768;

    // ---- phase 0: stage A(t+1); read A m0-3, B n0-1; MFMA Q0 ----
    if (t < 35) stageA(t + 1, cur ^ 1);
#pragma unroll
    for (int m = 0; m < 4; m++) {
      af[m][0] = *(const bf16x8*)(Ab + rbA + m * 2048 + swk[0]);
      af[m][1] = *(const bf16x8*)(Ab + rbA + m * 2048 + swk[1]);
    }
#pragma unroll
    for (int n = 0; n < 2; n++) {
      bf01[n][0] = *(const bf16x8*)(Bb + rbB + n * 2048 + swk[0]);
      bf01[n][1] = *(const bf16x8*)(Bb + rbB + n * 2048 + swk[1]);
    }
    BARRIER();
    __builtin_amdgcn_s_setprio(1);
#pragma unroll
    for (int m = 0; m < 4; m++)
#pragma unroll
      for (int n = 0; n < 2; n++) {
        acc[m][n] = __builtin_amdgcn_mfma_f32_16x16x32_bf16(af[m][0], bf01[n][0], acc[m][n], 0, 0, 0);
        acc[m][n] = __builtin_amdgcn_mfma_f32_16x16x32_bf16(af[m][1], bf01[n][1], acc[m][n], 0, 0, 0);
      }
    __builtin_amdgcn_s_setprio(0);
    BARRIER();

    // ---- phase 1: stage B(t+1); read B n2-3; MFMA Q1 ----
    if (t < 35) stageB(t + 1, cur ^ 1);
#pragma unroll
    for (int n = 0; n < 2; n++) {
      bf23[n][0] = *(const bf16x8*)(Bb + rbB + (n + 2) * 2048 + swk[0]);
      bf23[n][1] = *(const bf16x8*)(Bb + rbB + (n + 2) * 2048 + swk[1]);
    }
    BARRIER();
    __builtin_amdgcn_s_setprio(1);
#pragma unroll
    for (int m = 0; m < 4; m++)
#pragma unroll
      for (int n = 0; n < 2; n++) {
        acc[m][n + 2] = __builtin_amdgcn_mfma_f32_16x16x32_bf16(af[m][0], bf23[n][0], acc[m][n + 2], 0, 0, 0);
        acc[m][n + 2] = __builtin_amdgcn_mfma_f32_16x16x32_bf16(af[m][1], bf23[n][1], acc[m][n + 2], 0, 0, 0);
      }
    __builtin_amdgcn_s_setprio(0);
    BARRIER();

    // ---- phase 2: read A m4-7; MFMA Q2 ----
#pragma unroll
    for (int m = 0; m < 4; m++) {
      af[m][0] = *(const bf16x8*)(Ab + rbA + (m + 4) * 2048 + swk[0]);
      af[m][1] = *(const bf16x8*)(Ab + rbA + (m + 4) * 2048 + swk[1]);
    }
    BARRIER();
    __builtin_amdgcn_s_setprio(1);
#pragma unroll
    for (int m = 0; m < 4; m++)
#pragma unroll
      for (int n = 0; n < 2; n++) {
        acc[m + 4][n + 2] = __builtin_amdgcn_mfma_f32_16x16x32_bf16(af[m][0], bf23[n][0], acc[m + 4][n + 2], 0, 0, 0);
        acc[m + 4][n + 2] = __builtin_amdgcn_mfma_f32_16x16x32_bf16(af[m][1], bf23[n][1], acc[m + 4][n + 2], 0, 0, 0);
      }
    __builtin_amdgcn_s_setprio(0);
    BARRIER();

    // ---- phase 3: MFMA Q3; tile-boundary drain ----
    __builtin_amdgcn_s_setprio(1);
#pragma unroll
    for (int m = 0; m < 4; m++)
#pragma unroll
      for (int n = 0; n < 2; n++) {
        acc[m + 4][n] = __builtin_amdgcn_mfma_f32_16x16x32_bf16(af[m][0], bf01[n][0], acc[m + 4][n], 0, 0, 0);
        acc[m + 4][n] = __builtin_amdgcn_mfma_f32_16x16x32_bf16(af[m][1], bf01[n][1], acc[m + 4][n], 0, 0, 0);
      }
    __builtin_amdgcn_s_setprio(0);
    VMCNT0();
    BARRIER();
  }

  // ---- diagonal extraction (tiles tm==tn) ----
  if (tm == tn && (wc >> 1) == wr) {
#pragma unroll
    for (int n = 0; n < 4; n++) {
      const int m = (wc & 1) * 4 + n;
#pragma unroll
      for (int rg = 0; rg < 4; rg++) {
        if (l15 == g4 * 4 + rg) {
          const int row = tm * 256 + wr * 128 + m * 16 + l15;
          sdiag[b * NN + row] = acc[m][n][rg];
        }
      }
    }
  }

  // ---- per-row partial max / sumexp over this wave's 64 cols ----
  float* pmB = pm + ((size_t)(b * 32 + tn * 4 + wc)) * NN + tm * 256 + wr * 128;
  float* plB = pl + ((size_t)(b * 32 + tn * 4 + wc)) * NN + tm * 256 + wr * 128;
#pragma unroll
  for (int m = 0; m < 8; m++) {
#pragma unroll
    for (int rg = 0; rg < 4; rg++) {
      float v0 = acc[m][0][rg], v1 = acc[m][1][rg], v2 = acc[m][2][rg], v3 = acc[m][3][rg];
      float mx = fmaxf(fmaxf(v0, v1), fmaxf(v2, v3));
      mx = fmaxf(mx, __shfl_xor(mx, 1));
      mx = fmaxf(mx, __shfl_xor(mx, 2));
      mx = fmaxf(mx, __shfl_xor(mx, 4));
      mx = fmaxf(mx, __shfl_xor(mx, 8));
      float sm = __expf(v0 - mx) + __expf(v1 - mx) + __expf(v2 - mx) + __expf(v3 - mx);
      sm += __shfl_xor(sm, 1);
      sm += __shfl_xor(sm, 2);
      sm += __shfl_xor(sm, 4);
      sm += __shfl_xor(sm, 8);
      if (l15 == 0) {
        pmB[m * 16 + g4 * 4 + rg] = mx;
        plB[m * 16 + g4 * 4 + rg] = sm;
      }
    }
  }
}

// ---------------- combine partials + diag softmax ----------------
__global__ __launch_bounds__(256) void k_combine2(const float* __restrict__ pm,
                                                  const float* __restrict__ pl,
                                                  const float* __restrict__ sdiag,
                                                  float* __restrict__ mA,
                                                  float* __restrict__ lA,
                                                  float* __restrict__ dg) {
  int idx = blockIdx.x * 256 + threadIdx.x;  // b*NN + row
  int b = idx >> 11, row = idx & (NN - 1);
  const float* pmb = pm + (size_t)b * 32 * NN + row;
  const float* plb = pl + (size_t)b * 32 * NN + row;
  float m = -INFINITY;
#pragma unroll
  for (int c = 0; c < 32; c++) m = fmaxf(m, pmb[c * NN]);
  float l = 0.f;
#pragma unroll
  for (int c = 0; c < 32; c++) l += plb[c * NN] * __expf(pmb[c * NN] - m);
  mA[idx] = m;
  lA[idx] = l;
  dg[idx] = __expf(sdiag[idx] - m) / l;
}

// ---------------- fallback fp32 row stats ----------------
#define TI 32
#define TJ 128
#define DKK 32

__global__ __launch_bounds__(256) void k_rowstats(const float* __restrict__ q,
                                                  const float* __restrict__ k,
                                                  float* __restrict__ mOut,
                                                  float* __restrict__ lOut) {
  __shared__ float qs[DKK][TI];
  __shared__ float ks[DKK][TJ];
  const int b = blockIdx.y;
  const int r0 = blockIdx.x * TI;
  const int tid = threadIdx.x;
  const int tx = tid & 31;
  const int ty = tid >> 5;
  const float* qb = q + (size_t)b * NN * DD;
  const float* kb = k + (size_t)b * NN * DD;

  float mr[4], lr[4];
#pragma unroll
  for (int i = 0; i < 4; i++) { mr[i] = -INFINITY; lr[i] = 0.f; }

  const int qrow = tid >> 3;
  const int qkk = (tid & 7) * 4;

  for (int c0 = 0; c0 < NN; c0 += TJ) {
    float acc[4][4];
#pragma unroll
    for (int i = 0; i < 4; i++)
#pragma unroll
      for (int j = 0; j < 4; j++) acc[i][j] = 0.f;

    for (int d0 = 0; d0 < DD; d0 += DKK) {
      {
        float4 v = *(const float4*)&qb[(r0 + qrow) * DD + d0 + qkk];
        qs[qkk + 0][qrow] = v.x; qs[qkk + 1][qrow] = v.y;
        qs[qkk + 2][qrow] = v.z; qs[qkk + 3][qrow] = v.w;
      }
#pragma unroll
      for (int p = 0; p < 4; p++) {
        int f = tid + p * 256;
        int col = f >> 3;
        int kk = (f & 7) * 4;
        float4 v = *(const float4*)&kb[(c0 + col) * DD + d0 + kk];
        ks[kk + 0][col] = v.x; ks[kk + 1][col] = v.y;
        ks[kk + 2][col] = v.z; ks[kk + 3][col] = v.w;
      }
      __syncthreads();
#pragma unroll
      for (int kk = 0; kk < DKK; kk++) {
        float4 a = *(const float4*)&qs[kk][ty * 4];
        float4 bb4 = *(const float4*)&ks[kk][tx * 4];
        float av[4] = {a.x, a.y, a.z, a.w};
        float bv[4] = {bb4.x, bb4.y, bb4.z, bb4.w};
#pragma unroll
        for (int i = 0; i < 4; i++)
#pragma unroll
          for (int j = 0; j < 4; j++)
            acc[i][j] = fmaf(av[i], bv[j], acc[i][j]);
      }
      __syncthreads();
    }
#pragma unroll
    for (int i = 0; i < 4; i++) {
      float vmax = fmaxf(fmaxf(acc[i][0], acc[i][1]), fmaxf(acc[i][2], acc[i][3]));
      float nm = fmaxf(mr[i], vmax);
      float s = __expf(acc[i][0] - nm) + __expf(acc[i][1] - nm) +
                __expf(acc[i][2] - nm) + __expf(acc[i][3] - nm);
      lr[i] = lr[i] * __expf(mr[i] - nm) + s;
      mr[i] = nm;
    }
  }
#pragma unroll
  for (int i = 0; i < 4; i++) {
    float m = mr[i], l = lr[i];
    for (int off = 1; off < 32; off <<= 1) {
      float om = __shfl_xor(m, off);
      float ol = __shfl_xor(l, off);
      float nm = fmaxf(m, om);
      l = l * __expf(m - nm) + ol * __expf(om - nm);
      m = nm;
    }
    if (tx == 0) {
      int row = r0 + ty * 4 + i;
      mOut[b * NN + row] = m;
      lOut[b * NN + row] = l;
    }
  }
}

// ---------------- fallback diagonal softmax ----------------
__global__ __launch_bounds__(256) void k_diag(const float* __restrict__ q,
                                              const float* __restrict__ k,
                                              const float* __restrict__ mArr,
                                              const float* __restrict__ lArr,
                                              float* __restrict__ diag) {
  const int b = blockIdx.y;
  const int row = blockIdx.x * 64 + (threadIdx.x >> 2);
  const int part = threadIdx.x & 3;
  const float4* q4 = (const float4*)(q + ((size_t)b * NN + row) * DD);
  const float4* k4 = (const float4*)(k + ((size_t)b * NN + row) * DD);
  float s = 0.f;
  for (int t = part; t < DD / 4; t += 4) {
    float4 a = q4[t], c = k4[t];
    s += a.x * c.x + a.y * c.y + a.z * c.z + a.w * c.w;
  }
  s += __shfl_xor(s, 1);
  s += __shfl_xor(s, 2);
  if (part == 0) {
    int idx = b * NN + row;
    diag[idx] = __expf(s - mArr[idx]) / lArr[idx];
  }
}

// ---------------- per-batch selection ----------------
__global__ __launch_bounds__(256) void k_select(const float* __restrict__ q,
                                                const float* __restrict__ k,
                                                const float* __restrict__ mArr,
                                                const float* __restrict__ lArr,
                                                const float* __restrict__ diag,
                                                int* __restrict__ inst,
                                                int* __restrict__ pairs) {
  const int b = blockIdx.x;
  const int tid = threadIdx.x;
  __shared__ float sd[NN];
  __shared__ float rv[256];
  __shared__ int ri[256];
  __shared__ int schosen[KI];
  __shared__ int sinst[KI];
  __shared__ float srel[KI][KI];

  for (int r = tid; r < NN; r += 256) sd[r] = diag[b * NN + r];
  __syncthreads();

  for (int t = 0; t < KI; t++) {
    float bv = -1e30f;
    int bi = NN;
    for (int r = tid; r < NN; r += 256) {
      float v = sd[r];
      if (v > bv || (v == bv && r < bi)) { bv = v; bi = r; }
    }
    rv[tid] = bv; ri[tid] = bi;
    __syncthreads();
    for (int s = 128; s > 0; s >>= 1) {
      if (tid < s) {
        float ov = rv[tid + s]; int oi = ri[tid + s];
        if (ov > rv[tid] || (ov == rv[tid] && oi < ri[tid])) { rv[tid] = ov; ri[tid] = oi; }
      }
      __syncthreads();
    }
    if (tid == 0) { schosen[t] = ri[0]; sd[ri[0]] = -1.f; }
    __syncthreads();
  }
  if (tid == 0) {
    for (int i = 1; i < KI; i++) {
      int v = schosen[i]; int j = i - 1;
      while (j >= 0 && schosen[j] > v) { schosen[j + 1] = schosen[j]; j--; }
      schosen[j + 1] = v;
    }
    for (int i = 0; i < KI; i++) { sinst[i] = schosen[i]; inst[b * KI + i] = schosen[i]; }
  }
  __syncthreads();

  if (tid < KI * KI) {
    int a = tid / KI, c = tid % KI;
    int ia = sinst[a], ic = sinst[c];
    const float4* qa = (const float4*)(q + ((size_t)b * NN + ia) * DD);
    const float4* kc = (const float4*)(k + ((size_t)b * NN + ic) * DD);
    float s = 0.f;
    for (int t = 0; t < DD / 4; t++) {
      float4 x = qa[t], y = kc[t];
      s += x.x * y.x + x.y * y.y + x.z * y.z + x.w * y.w;
    }
    srel[a][c] = __expf(s - mArr[b * NN + ia]) / lArr[b * NN + ia];
  }
  __syncthreads();

  if (tid < KI) {
    int a = tid;
    float v[KI];
    bool mk[KI];
    for (int c = 0; c < KI; c++) { v[c] = srel[a][c]; mk[c] = false; }
    for (int r = 0; r < KR; r++) {
      float bv = -1e30f; int bi = -1;
      for (int c = 0; c < KI; c++)
        if (!mk[c] && v[c] > bv) { bv = v[c]; bi = c; }
      mk[bi] = true;
    }
    int r = 0;
    for (int c = 0; c < KI; c++)
      if (mk[c]) {
        int p = (b * KI * KR + a * KR + r) * 2;
        pairs[p] = sinst[a];
        pairs[p + 1] = sinst[c];
        r++;
      }
  }
}

// ---------------- gather outputs ----------------
__global__ __launch_bounds__(192) void k_gather(const float* __restrict__ q,
                                                const int* __restrict__ pairs,
                                                float* __restrict__ out) {
  const int p = blockIdx.x;
  const int b = p / (KI * KR);
  const int si = pairs[p * 2];
  const int oi = pairs[p * 2 + 1];
  const int t = threadIdx.x;
  const float4* qs4 = (const float4*)(q + ((size_t)b * NN + si) * DD);
  const float4* qo4 = (const float4*)(q + ((size_t)b * NN + oi) * DD);
  float4 s4 = qs4[t];
  float4 o4 = qo4[t];
  float4* o = (float4*)out;
  const int SEC = BB * KI * KR * DD / 4;
  o[p * (DD / 4) + t] = s4;
  o[SEC + p * (DD / 4) + t] = o4;
  float4 r4;
  r4.x = s4.x + o4.x; r4.y = s4.y + o4.y; r4.z = s4.z + o4.z; r4.w = s4.w + o4.w;
  o[2 * SEC + p * (DD / 4) + t] = r4;
}

extern "C" void kernel_launch(void* const* d_in, const int* in_sizes, int n_in,
                              void* d_out, int out_size, void* d_ws, size_t ws_size,
                              hipStream_t stream) {
  const float* q = (const float*)d_in[0];
  const float* k = (const float*)d_in[1];
  char* ws = (char*)d_ws;

  const size_t S2 = (size_t)BB * NN * DD * 2;  // bytes of one bf16 tensor
  const size_t P = (size_t)BB * 32 * NN * 4;   // partial stats
  const size_t M4 = (size_t)BB * NN * 4;
  const size_t need = 4 * S2 + 2 * P + 4 * M4 + 65536;

  if (ws_size >= need) {
    unsigned short* qh = (unsigned short*)ws;
    unsigned short* ql = (unsigned short*)(ws + S2);
    unsigned short* kh = (unsigned short*)(ws + 2 * S2);
    unsigned short* kl = (unsigned short*)(ws + 3 * S2);
    float* pm = (float*)(ws + 4 * S2);
    float* pl = (float*)(ws + 4 * S2 + P);
    float* sdg = (float*)(ws + 4 * S2 + 2 * P);
    float* mA = sdg + BB * NN;
    float* lA = mA + BB * NN;
    float* dg = lA + BB * NN;
    int* inst = (int*)(dg + BB * NN);
    int* pairs = inst + BB * KI;

    k_split<<<dim3(2048, 2), 256, 0, stream>>>(q, k, qh, ql, kh, kl);
    (void)hipFuncSetAttribute((const void*)k_mfma8,
                              hipFuncAttributeMaxDynamicSharedMemorySize, 131072);
    k_mfma8<<<dim3(64, BB), 512, 131072, stream>>>(qh, ql, kh, kl, pm, pl, sdg);
    k_combine2<<<BB * NN / 256, 256, 0, stream>>>(pm, pl, sdg, mA, lA, dg);
    k_select<<<BB, 256, 0, stream>>>(q, k, mA, lA, dg, inst, pairs);
    k_gather<<<BB * KI * KR, 192, 0, stream>>>(q, pairs, (float*)d_out);
  } else {
    float* mA = (float*)ws;
    float* lA = mA + BB * NN;
    float* dg = lA + BB * NN;
    int* inst = (int*)(dg + BB * NN);
    int* pairs = inst + BB * KI;

    dim3 g1(NN / TI, BB);
    k_rowstats<<<g1, 256, 0, stream>>>(q, k, mA, lA);
    dim3 g1b(NN / 64, BB);
    k_diag<<<g1b, 256, 0, stream>>>(q, k, mA, lA, dg);
    k_select<<<BB, 256, 0, stream>>>(q, k, mA, lA, dg, inst, pairs);
    k_gather<<<BB * KI * KR, 192, 0, stream>>>(q, pairs, (float*)d_out);
  }
}

// Round 6
// 287.113 us; speedup vs baseline: 1.0004x; 1.0004x over previous
//
#include <hip/hip_runtime.h>

#define BB 8
#define NN 2048
#define DD 768
#define KI 10
#define KR 5

typedef __attribute__((ext_vector_type(8))) short bf16x8;
typedef __attribute__((ext_vector_type(4))) float f32x4;

#define FENCE() asm volatile("" ::: "memory")
#define BARRIER() do { FENCE(); __builtin_amdgcn_s_barrier(); FENCE(); } while (0)
#define VMCNT0() asm volatile("s_waitcnt vmcnt(0)" ::: "memory")

__device__ __forceinline__ void async_copy16(void* ldsp, const void* g) {
  __builtin_amdgcn_global_load_lds(
      (const __attribute__((address_space(1))) unsigned int*)g,
      (__attribute__((address_space(3))) unsigned int*)ldsp, 16, 0, 0);
}

__device__ __forceinline__ unsigned short f2bf_rn(float x) {
  unsigned u = __float_as_uint(x);
  unsigned r = (u + 0x7fffu + ((u >> 16) & 1u)) >> 16;
  return (unsigned short)r;
}

// ---------------- split fp32 -> bf16 hi/lo ----------------
__global__ __launch_bounds__(256) void k_split(const float* __restrict__ q,
                                               const float* __restrict__ k,
                                               unsigned short* __restrict__ qh,
                                               unsigned short* __restrict__ ql,
                                               unsigned short* __restrict__ kh,
                                               unsigned short* __restrict__ kl) {
  const int n4 = BB * NN * DD / 4;
  const float4* src = (const float4*)(blockIdx.y ? k : q);
  ushort4* h = (ushort4*)(blockIdx.y ? kh : qh);
  ushort4* lo = (ushort4*)(blockIdx.y ? kl : ql);
  for (int i = blockIdx.x * blockDim.x + threadIdx.x; i < n4;
       i += gridDim.x * blockDim.x) {
    float4 v = src[i];
    ushort4 hv, lv;
    hv.x = f2bf_rn(v.x); lv.x = f2bf_rn(v.x - __uint_as_float((unsigned)hv.x << 16));
    hv.y = f2bf_rn(v.y); lv.y = f2bf_rn(v.y - __uint_as_float((unsigned)hv.y << 16));
    hv.z = f2bf_rn(v.z); lv.z = f2bf_rn(v.z - __uint_as_float((unsigned)hv.z << 16));
    hv.w = f2bf_rn(v.w); lv.w = f2bf_rn(v.w - __uint_as_float((unsigned)hv.w << 16));
    h[i] = hv; lo[i] = lv;
  }
}

// ---------------- 256x256-tile pipelined MFMA row-stats kernel ----------------
// 8 waves (2x4), BK=64, double-buffered 128KB LDS, XOR slot-swizzle.
// Register-lean phases: fragments re-read per phase, peak live = acc128+a64+b32.
__global__ __launch_bounds__(512, 2) void k_mfma8(const unsigned short* __restrict__ qh,
                                                  const unsigned short* __restrict__ ql,
                                                  const unsigned short* __restrict__ kh,
                                                  const unsigned short* __restrict__ kl,
                                                  float* __restrict__ pm,
                                                  float* __restrict__ pl,
                                                  float* __restrict__ sdiag) {
  extern __shared__ char lds[];
  const int flat = blockIdx.y * 64 + blockIdx.x;      // 0..511
  const int nid = (flat & 7) * 64 + (flat >> 3);      // chunked: one batch per XCD
  const int b = nid >> 6;
  const int tile = nid & 63;
  const int tm = tile >> 3, tn = tile & 7;
  const int tid = threadIdx.x;
  const int w = tid >> 6, lane = tid & 63;
  const int wr = w >> 2, wc = w & 3;
  const int l15 = lane & 15, g4 = lane >> 4;

  const size_t bOff = (size_t)b * NN * (DD * 2);
  const char* Aq = (const char*)qh + bOff;
  const char* Al = (const char*)ql + bOff;
  const char* Bh = (const char*)kh + bOff;
  const char* Bl = (const char*)kl + bOff;

  // staging maps: LDS linear 1KB chunks -> inverse-swizzled global source
  int aSrc[4], bSrc[4], ldsOff[4];
#pragma unroll
  for (int e = 0; e < 4; e++) {
    const int chunk = e * 8 + w;                 // 0..31
    const int r = chunk * 8 + (lane >> 3);       // row 0..255 in tile
    const int sw = ((lane & 7) ^ (lane >> 3)) << 4;
    aSrc[e] = (tm * 256 + r) * 1536 + sw;
    bSrc[e] = (tn * 256 + r) * 1536 + sw;
    ldsOff[e] = chunk * 1024;                    // wave-uniform LDS dest
  }

  // fragment-read bases (swizzled slot lookup)
  const int rbA = (wr * 128 + l15) * 128;
  const int rbB = (wc * 64 + l15) * 128;
  int swk[2];
  swk[0] = (g4 ^ (lane & 7)) << 4;
  swk[1] = ((4 + g4) ^ (lane & 7)) << 4;

  f32x4 acc[8][4];
#pragma unroll
  for (int i = 0; i < 8; i++)
#pragma unroll
    for (int j = 0; j < 4; j++) acc[i][j] = (f32x4){0.f, 0.f, 0.f, 0.f};

  auto stageA = [&](int u, int buf) {
    const int seg = u / 12;
    const char* S = ((seg < 2) ? Aq : Al) + (u - seg * 12) * 128;
#pragma unroll
    for (int e = 0; e < 4; e++)
      async_copy16(lds + buf * 65536 + ldsOff[e], S + aSrc[e]);
  };
  auto stageB = [&](int u, int buf) {
    const int seg = u / 12;
    const char* S = ((seg == 1) ? Bl : Bh) + (u - seg * 12) * 128;
#pragma unroll
    for (int e = 0; e < 4; e++)
      async_copy16(lds + buf * 65536 + 32768 + ldsOff[e], S + bSrc[e]);
  };

  // prologue: tile 0 into buf 0
  stageA(0, 0);
  stageB(0, 0);
  VMCNT0();
  BARRIER();

  for (int t = 0; t < 36; ++t) {
    const int cur = t & 1;
    const char* Ab = lds + cur * 65536;
    const char* Bb = Ab + 32768;
    bf16x8 a[4][2], bq[2][2];

    // ---- phase 0: stage A(t+1); read a m0-3, b n0-1; MFMA Q0 ----
    if (t < 35) stageA(t + 1, cur ^ 1);
#pragma unroll
    for (int m = 0; m < 4; m++) {
      a[m][0] = *(const bf16x8*)(Ab + rbA + m * 2048 + swk[0]);
      a[m][1] = *(const bf16x8*)(Ab + rbA + m * 2048 + swk[1]);
    }
#pragma unroll
    for (int n = 0; n < 2; n++) {
      bq[n][0] = *(const bf16x8*)(Bb + rbB + n * 2048 + swk[0]);
      bq[n][1] = *(const bf16x8*)(Bb + rbB + n * 2048 + swk[1]);
    }
    BARRIER();
    __builtin_amdgcn_s_setprio(1);
#pragma unroll
    for (int m = 0; m < 4; m++)
#pragma unroll
      for (int n = 0; n < 2; n++) {
        acc[m][n] = __builtin_amdgcn_mfma_f32_16x16x32_bf16(a[m][0], bq[n][0], acc[m][n], 0, 0, 0);
        acc[m][n] = __builtin_amdgcn_mfma_f32_16x16x32_bf16(a[m][1], bq[n][1], acc[m][n], 0, 0, 0);
      }
    __builtin_amdgcn_s_setprio(0);
    BARRIER();

    // ---- phase 1: stage B(t+1); re-read b n2-3; MFMA Q1 (a stays live) ----
    if (t < 35) stageB(t + 1, cur ^ 1);
#pragma unroll
    for (int n = 0; n < 2; n++) {
      bq[n][0] = *(const bf16x8*)(Bb + rbB + (n + 2) * 2048 + swk[0]);
      bq[n][1] = *(const bf16x8*)(Bb + rbB + (n + 2) * 2048 + swk[1]);
    }
    BARRIER();
    __builtin_amdgcn_s_setprio(1);
#pragma unroll
    for (int m = 0; m < 4; m++)
#pragma unroll
      for (int n = 0; n < 2; n++) {
        acc[m][n + 2] = __builtin_amdgcn_mfma_f32_16x16x32_bf16(a[m][0], bq[n][0], acc[m][n + 2], 0, 0, 0);
        acc[m][n + 2] = __builtin_amdgcn_mfma_f32_16x16x32_bf16(a[m][1], bq[n][1], acc[m][n + 2], 0, 0, 0);
      }
    __builtin_amdgcn_s_setprio(0);
    BARRIER();

    // ---- phase 2: re-read a m4-7; MFMA Q2 (b n2-3 stays live) ----
#pragma unroll
    for (int m = 0; m < 4; m++) {
      a[m][0] = *(const bf16x8*)(Ab + rbA + (m + 4) * 2048 + swk[0]);
      a[m][1] = *(const bf16x8*)(Ab + rbA + (m + 4) * 2048 + swk[1]);
    }
    BARRIER();
    __builtin_amdgcn_s_setprio(1);
#pragma unroll
    for (int m = 0; m < 4; m++)
#pragma unroll
      for (int n = 0; n < 2; n++) {
        acc[m + 4][n + 2] = __builtin_amdgcn_mfma_f32_16x16x32_bf16(a[m][0], bq[n][0], acc[m + 4][n + 2], 0, 0, 0);
        acc[m + 4][n + 2] = __builtin_amdgcn_mfma_f32_16x16x32_bf16(a[m][1], bq[n][1], acc[m + 4][n + 2], 0, 0, 0);
      }
    __builtin_amdgcn_s_setprio(0);
    BARRIER();

    // ---- phase 3: re-read b n0-1; MFMA Q3; tile-boundary drain ----
#pragma unroll
    for (int n = 0; n < 2; n++) {
      bq[n][0] = *(const bf16x8*)(Bb + rbB + n * 2048 + swk[0]);
      bq[n][1] = *(const bf16x8*)(Bb + rbB + n * 2048 + swk[1]);
    }
    BARRIER();
    __builtin_amdgcn_s_setprio(1);
#pragma unroll
    for (int m = 0; m < 4; m++)
#pragma unroll
      for (int n = 0; n < 2; n++) {
        acc[m + 4][n] = __builtin_amdgcn_mfma_f32_16x16x32_bf16(a[m][0], bq[n][0], acc[m + 4][n], 0, 0, 0);
        acc[m + 4][n] = __builtin_amdgcn_mfma_f32_16x16x32_bf16(a[m][1], bq[n][1], acc[m + 4][n], 0, 0, 0);
      }
    __builtin_amdgcn_s_setprio(0);
    VMCNT0();
    BARRIER();
  }

  // ---- diagonal extraction (tiles tm==tn) ----
  if (tm == tn && (wc >> 1) == wr) {
#pragma unroll
    for (int n = 0; n < 4; n++) {
      const int m = (wc & 1) * 4 + n;
#pragma unroll
      for (int rg = 0; rg < 4; rg++) {
        if (l15 == g4 * 4 + rg) {
          const int row = tm * 256 + wr * 128 + m * 16 + l15;
          sdiag[b * NN + row] = acc[m][n][rg];
        }
      }
    }
  }

  // ---- per-row partial max / sumexp over this wave's 64 cols ----
  float* pmB = pm + ((size_t)(b * 32 + tn * 4 + wc)) * NN + tm * 256 + wr * 128;
  float* plB = pl + ((size_t)(b * 32 + tn * 4 + wc)) * NN + tm * 256 + wr * 128;
#pragma unroll
  for (int m = 0; m < 8; m++) {
#pragma unroll
    for (int rg = 0; rg < 4; rg++) {
      float v0 = acc[m][0][rg], v1 = acc[m][1][rg], v2 = acc[m][2][rg], v3 = acc[m][3][rg];
      float mx = fmaxf(fmaxf(v0, v1), fmaxf(v2, v3));
      mx = fmaxf(mx, __shfl_xor(mx, 1));
      mx = fmaxf(mx, __shfl_xor(mx, 2));
      mx = fmaxf(mx, __shfl_xor(mx, 4));
      mx = fmaxf(mx, __shfl_xor(mx, 8));
      float sm = __expf(v0 - mx) + __expf(v1 - mx) + __expf(v2 - mx) + __expf(v3 - mx);
      sm += __shfl_xor(sm, 1);
      sm += __shfl_xor(sm, 2);
      sm += __shfl_xor(sm, 4);
      sm += __shfl_xor(sm, 8);
      if (l15 == 0) {
        pmB[m * 16 + g4 * 4 + rg] = mx;
        plB[m * 16 + g4 * 4 + rg] = sm;
      }
    }
  }
}

// ---------------- combine partials + diag softmax ----------------
__global__ __launch_bounds__(256) void k_combine2(const float* __restrict__ pm,
                                                  const float* __restrict__ pl,
                                                  const float* __restrict__ sdiag,
                                                  float* __restrict__ mA,
                                                  float* __restrict__ lA,
                                                  float* __restrict__ dg) {
  int idx = blockIdx.x * 256 + threadIdx.x;  // b*NN + row
  int b = idx >> 11, row = idx & (NN - 1);
  const float* pmb = pm + (size_t)b * 32 * NN + row;
  const float* plb = pl + (size_t)b * 32 * NN + row;
  float m = -INFINITY;
#pragma unroll
  for (int c = 0; c < 32; c++) m = fmaxf(m, pmb[c * NN]);
  float l = 0.f;
#pragma unroll
  for (int c = 0; c < 32; c++) l += plb[c * NN] * __expf(pmb[c * NN] - m);
  mA[idx] = m;
  lA[idx] = l;
  dg[idx] = __expf(sdiag[idx] - m) / l;
}

// ---------------- fallback fp32 row stats ----------------
#define TI 32
#define TJ 128
#define DKK 32

__global__ __launch_bounds__(256) void k_rowstats(const float* __restrict__ q,
                                                  const float* __restrict__ k,
                                                  float* __restrict__ mOut,
                                                  float* __restrict__ lOut) {
  __shared__ float qs[DKK][TI];
  __shared__ float ks[DKK][TJ];
  const int b = blockIdx.y;
  const int r0 = blockIdx.x * TI;
  const int tid = threadIdx.x;
  const int tx = tid & 31;
  const int ty = tid >> 5;
  const float* qb = q + (size_t)b * NN * DD;
  const float* kb = k + (size_t)b * NN * DD;

  float mr[4], lr[4];
#pragma unroll
  for (int i = 0; i < 4; i++) { mr[i] = -INFINITY; lr[i] = 0.f; }

  const int qrow = tid >> 3;
  const int qkk = (tid & 7) * 4;

  for (int c0 = 0; c0 < NN; c0 += TJ) {
    float acc[4][4];
#pragma unroll
    for (int i = 0; i < 4; i++)
#pragma unroll
      for (int j = 0; j < 4; j++) acc[i][j] = 0.f;

    for (int d0 = 0; d0 < DD; d0 += DKK) {
      {
        float4 v = *(const float4*)&qb[(r0 + qrow) * DD + d0 + qkk];
        qs[qkk + 0][qrow] = v.x; qs[qkk + 1][qrow] = v.y;
        qs[qkk + 2][qrow] = v.z; qs[qkk + 3][qrow] = v.w;
      }
#pragma unroll
      for (int p = 0; p < 4; p++) {
        int f = tid + p * 256;
        int col = f >> 3;
        int kk = (f & 7) * 4;
        float4 v = *(const float4*)&kb[(c0 + col) * DD + d0 + kk];
        ks[kk + 0][col] = v.x; ks[kk + 1][col] = v.y;
        ks[kk + 2][col] = v.z; ks[kk + 3][col] = v.w;
      }
      __syncthreads();
#pragma unroll
      for (int kk = 0; kk < DKK; kk++) {
        float4 a = *(const float4*)&qs[kk][ty * 4];
        float4 bb4 = *(const float4*)&ks[kk][tx * 4];
        float av[4] = {a.x, a.y, a.z, a.w};
        float bv[4] = {bb4.x, bb4.y, bb4.z, bb4.w};
#pragma unroll
        for (int i = 0; i < 4; i++)
#pragma unroll
          for (int j = 0; j < 4; j++)
            acc[i][j] = fmaf(av[i], bv[j], acc[i][j]);
      }
      __syncthreads();
    }
#pragma unroll
    for (int i = 0; i < 4; i++) {
      float vmax = fmaxf(fmaxf(acc[i][0], acc[i][1]), fmaxf(acc[i][2], acc[i][3]));
      float nm = fmaxf(mr[i], vmax);
      float s = __expf(acc[i][0] - nm) + __expf(acc[i][1] - nm) +
                __expf(acc[i][2] - nm) + __expf(acc[i][3] - nm);
      lr[i] = lr[i] * __expf(mr[i] - nm) + s;
      mr[i] = nm;
    }
  }
#pragma unroll
  for (int i = 0; i < 4; i++) {
    float m = mr[i], l = lr[i];
    for (int off = 1; off < 32; off <<= 1) {
      float om = __shfl_xor(m, off);
      float ol = __shfl_xor(l, off);
      float nm = fmaxf(m, om);
      l = l * __expf(m - nm) + ol * __expf(om - nm);
      m = nm;
    }
    if (tx == 0) {
      int row = r0 + ty * 4 + i;
      mOut[b * NN + row] = m;
      lOut[b * NN + row] = l;
    }
  }
}

// ---------------- fallback diagonal softmax ----------------
__global__ __launch_bounds__(256) void k_diag(const float* __restrict__ q,
                                              const float* __restrict__ k,
                                              const float* __restrict__ mArr,
                                              const float* __restrict__ lArr,
                                              float* __restrict__ diag) {
  const int b = blockIdx.y;
  const int row = blockIdx.x * 64 + (threadIdx.x >> 2);
  const int part = threadIdx.x & 3;
  const float4* q4 = (const float4*)(q + ((size_t)b * NN + row) * DD);
  const float4* k4 = (const float4*)(k + ((size_t)b * NN + row) * DD);
  float s = 0.f;
  for (int t = part; t < DD / 4; t += 4) {
    float4 a = q4[t], c = k4[t];
    s += a.x * c.x + a.y * c.y + a.z * c.z + a.w * c.w;
  }
  s += __shfl_xor(s, 1);
  s += __shfl_xor(s, 2);
  if (part == 0) {
    int idx = b * NN + row;
    diag[idx] = __expf(s - mArr[idx]) / lArr[idx];
  }
}

// ---------------- per-batch selection ----------------
__global__ __launch_bounds__(256) void k_select(const float* __restrict__ q,
                                                const float* __restrict__ k,
                                                const float* __restrict__ mArr,
                                                const float* __restrict__ lArr,
                                                const float* __restrict__ diag,
                                                int* __restrict__ inst,
                                                int* __restrict__ pairs) {
  const int b = blockIdx.x;
  const int tid = threadIdx.x;
  __shared__ float sd[NN];
  __shared__ float rv[256];
  __shared__ int ri[256];
  __shared__ int schosen[KI];
  __shared__ int sinst[KI];
  __shared__ float srel[KI][KI];

  for (int r = tid; r < NN; r += 256) sd[r] = diag[b * NN + r];
  __syncthreads();

  for (int t = 0; t < KI; t++) {
    float bv = -1e30f;
    int bi = NN;
    for (int r = tid; r < NN; r += 256) {
      float v = sd[r];
      if (v > bv || (v == bv && r < bi)) { bv = v; bi = r; }
    }
    rv[tid] = bv; ri[tid] = bi;
    __syncthreads();
    for (int s = 128; s > 0; s >>= 1) {
      if (tid < s) {
        float ov = rv[tid + s]; int oi = ri[tid + s];
        if (ov > rv[tid] || (ov == rv[tid] && oi < ri[tid])) { rv[tid] = ov; ri[tid] = oi; }
      }
      __syncthreads();
    }
    if (tid == 0) { schosen[t] = ri[0]; sd[ri[0]] = -1.f; }
    __syncthreads();
  }
  if (tid == 0) {
    for (int i = 1; i < KI; i++) {
      int v = schosen[i]; int j = i - 1;
      while (j >= 0 && schosen[j] > v) { schosen[j + 1] = schosen[j]; j--; }
      schosen[j + 1] = v;
    }
    for (int i = 0; i < KI; i++) { sinst[i] = schosen[i]; inst[b * KI + i] = schosen[i]; }
  }
  __syncthreads();

  if (tid < KI * KI) {
    int a = tid / KI, c = tid % KI;
    int ia = sinst[a], ic = sinst[c];
    const float4* qa = (const float4*)(q + ((size_t)b * NN + ia) * DD);
    const float4* kc = (const float4*)(k + ((size_t)b * NN + ic) * DD);
    float s = 0.f;
    for (int t = 0; t < DD / 4; t++) {
      float4 x = qa[t], y = kc[t];
      s += x.x * y.x + x.y * y.y + x.z * y.z + x.w * y.w;
    }
    srel[a][c] = __expf(s - mArr[b * NN + ia]) / lArr[b * NN + ia];
  }
  __syncthreads();

  if (tid < KI) {
    int a = tid;
    float v[KI];
    bool mk[KI];
    for (int c = 0; c < KI; c++) { v[c] = srel[a][c]; mk[c] = false; }
    for (int r = 0; r < KR; r++) {
      float bv = -1e30f; int bi = -1;
      for (int c = 0; c < KI; c++)
        if (!mk[c] && v[c] > bv) { bv = v[c]; bi = c; }
      mk[bi] = true;
    }
    int r = 0;
    for (int c = 0; c < KI; c++)
      if (mk[c]) {
        int p = (b * KI * KR + a * KR + r) * 2;
        pairs[p] = sinst[a];
        pairs[p + 1] = sinst[c];
        r++;
      }
  }
}

// ---------------- gather outputs ----------------
__global__ __launch_bounds__(192) void k_gather(const float* __restrict__ q,
                                                const int* __restrict__ pairs,
                                                float* __restrict__ out) {
  const int p = blockIdx.x;
  const int b = p / (KI * KR);
  const int si = pairs[p * 2];
  const int oi = pairs[p * 2 + 1];
  const int t = threadIdx.x;
  const float4* qs4 = (const float4*)(q + ((size_t)b * NN + si) * DD);
  const float4* qo4 = (const float4*)(q + ((size_t)b * NN + oi) * DD);
  float4 s4 = qs4[t];
  float4 o4 = qo4[t];
  float4* o = (float4*)out;
  const int SEC = BB * KI * KR * DD / 4;
  o[p * (DD / 4) + t] = s4;
  o[SEC + p * (DD / 4) + t] = o4;
  float4 r4;
  r4.x = s4.x + o4.x; r4.y = s4.y + o4.y; r4.z = s4.z + o4.z; r4.w = s4.w + o4.w;
  o[2 * SEC + p * (DD / 4) + t] = r4;
}

extern "C" void kernel_launch(void* const* d_in, const int* in_sizes, int n_in,
                              void* d_out, int out_size, void* d_ws, size_t ws_size,
                              hipStream_t stream) {
  const float* q = (const float*)d_in[0];
  const float* k = (const float*)d_in[1];
  char* ws = (char*)d_ws;

  const size_t S2 = (size_t)BB * NN * DD * 2;  // bytes of one bf16 tensor
  const size_t P = (size_t)BB * 32 * NN * 4;   // partial stats
  const size_t M4 = (size_t)BB * NN * 4;
  const size_t need = 4 * S2 + 2 * P + 4 * M4 + 65536;

  if (ws_size >= need) {
    unsigned short* qh = (unsigned short*)ws;
    unsigned short* ql = (unsigned short*)(ws + S2);
    unsigned short* kh = (unsigned short*)(ws + 2 * S2);
    unsigned short* kl = (unsigned short*)(ws + 3 * S2);
    float* pm = (float*)(ws + 4 * S2);
    float* pl = (float*)(ws + 4 * S2 + P);
    float* sdg = (float*)(ws + 4 * S2 + 2 * P);
    float* mA = sdg + BB * NN;
    float* lA = mA + BB * NN;
    float* dg = lA + BB * NN;
    int* inst = (int*)(dg + BB * NN);
    int* pairs = inst + BB * KI;

    k_split<<<dim3(2048, 2), 256, 0, stream>>>(q, k, qh, ql, kh, kl);
    (void)hipFuncSetAttribute((const void*)k_mfma8,
                              hipFuncAttributeMaxDynamicSharedMemorySize, 131072);
    k_mfma8<<<dim3(64, BB), 512, 131072, stream>>>(qh, ql, kh, kl, pm, pl, sdg);
    k_combine2<<<BB * NN / 256, 256, 0, stream>>>(pm, pl, sdg, mA, lA, dg);
    k_select<<<BB, 256, 0, stream>>>(q, k, mA, lA, dg, inst, pairs);
    k_gather<<<BB * KI * KR, 192, 0, stream>>>(q, pairs, (float*)d_out);
  } else {
    float* mA = (float*)ws;
    float* lA = mA + BB * NN;
    float* dg = lA + BB * NN;
    int* inst = (int*)(dg + BB * NN);
    int* pairs = inst + BB * KI;

    dim3 g1(NN / TI, BB);
    k_rowstats<<<g1, 256, 0, stream>>>(q, k, mA, lA);
    dim3 g1b(NN / 64, BB);
    k_diag<<<g1b, 256, 0, stream>>>(q, k, mA, lA, dg);
    k_select<<<BB, 256, 0, stream>>>(q, k, mA, lA, dg, inst, pairs);
    k_gather<<<BB * KI * KR, 192, 0, stream>>>(q, pairs, (float*)d_out);
  }
}

// Round 7
// 240.123 us; speedup vs baseline: 1.1961x; 1.1957x over previous
//
#include <hip/hip_runtime.h>

#define BB 8
#define NN 2048
#define DD 768
#define KI 10
#define KR 5

typedef __attribute__((ext_vector_type(8))) short bf16x8;
typedef __attribute__((ext_vector_type(4))) float f32x4;

__device__ __forceinline__ void async_copy16(void* ldsp, const void* g) {
  __builtin_amdgcn_global_load_lds(
      (const __attribute__((address_space(1))) unsigned int*)g,
      (__attribute__((address_space(3))) unsigned int*)ldsp, 16, 0, 0);
}

__device__ __forceinline__ unsigned short f2bf_rn(float x) {
  unsigned u = __float_as_uint(x);
  unsigned r = (u + 0x7fffu + ((u >> 16) & 1u)) >> 16;
  return (unsigned short)r;
}

// ---------------- split fp32 -> bf16 hi/lo ----------------
__global__ __launch_bounds__(256) void k_split(const float* __restrict__ q,
                                               const float* __restrict__ k,
                                               unsigned short* __restrict__ qh,
                                               unsigned short* __restrict__ ql,
                                               unsigned short* __restrict__ kh,
                                               unsigned short* __restrict__ kl) {
  const int n4 = BB * NN * DD / 4;
  const float4* src = (const float4*)(blockIdx.y ? k : q);
  ushort4* h = (ushort4*)(blockIdx.y ? kh : qh);
  ushort4* lo = (ushort4*)(blockIdx.y ? kl : ql);
  for (int i = blockIdx.x * blockDim.x + threadIdx.x; i < n4;
       i += gridDim.x * blockDim.x) {
    float4 v = src[i];
    ushort4 hv, lv;
    hv.x = f2bf_rn(v.x); lv.x = f2bf_rn(v.x - __uint_as_float((unsigned)hv.x << 16));
    hv.y = f2bf_rn(v.y); lv.y = f2bf_rn(v.y - __uint_as_float((unsigned)hv.y << 16));
    hv.z = f2bf_rn(v.z); lv.z = f2bf_rn(v.z - __uint_as_float((unsigned)hv.z << 16));
    hv.w = f2bf_rn(v.w); lv.w = f2bf_rn(v.w - __uint_as_float((unsigned)hv.w << 16));
    h[i] = hv; lo[i] = lv;
  }
}

// ---------------- MFMA tile kernel (proven round-4 structure) ----------------
// 128x128 tile, 4 waves (2x2 of 64x64), BK=64 bf16, XOR-swizzled LDS,
// + chunked XCD swizzle (one batch per XCD) + fused diagonal extraction.
__global__ __launch_bounds__(256, 4) void k_mfma(const unsigned short* __restrict__ qh,
                                                 const unsigned short* __restrict__ ql,
                                                 const unsigned short* __restrict__ kh,
                                                 const unsigned short* __restrict__ kl,
                                                 float* __restrict__ pm,
                                                 float* __restrict__ pl,
                                                 float* __restrict__ sdiag) {
  __shared__ short As[128 * 64];
  __shared__ short Bs[128 * 64];
  const int flat = blockIdx.y * 256 + blockIdx.x;     // 0..2047
  const int nid = (flat & 7) * 256 + (flat >> 3);     // chunked: one batch per XCD
  const int b = nid >> 8;
  const int tile = nid & 255;
  const int tm = tile >> 4;
  const int tn = tile & 15;
  const int tid = threadIdx.x;
  const int w = tid >> 6, lane = tid & 63;
  const int wr = w >> 1, wc = w & 1;
  const int l15 = lane & 15, g4 = lane >> 4;

  // staging precompute: LDS linear byte L -> global (row, swizzled k-slot)
  int stageOff[4];
  char* ldsA[4];
  char* ldsB[4];
#pragma unroll
  for (int p = 0; p < 4; p++) {
    int L = w * 4096 + p * 1024 + lane * 16;
    int row = L >> 7;            // 128B per LDS row (64 bf16)
    int s = (L >> 4) & 7;        // 16B slot within row
    stageOff[p] = row * (DD * 2) + ((s ^ (row & 7)) << 4);
    ldsA[p] = (char*)As + w * 4096 + p * 1024;
    ldsB[p] = (char*)Bs + w * 4096 + p * 1024;
  }
  const size_t abase = ((size_t)b * NN + (size_t)tm * 128) * (DD * 2);
  const size_t bbase = ((size_t)b * NN + (size_t)tn * 128) * (DD * 2);
  const char* segA[3] = {(const char*)qh + abase, (const char*)qh + abase,
                         (const char*)ql + abase};
  const char* segB[3] = {(const char*)kh + bbase, (const char*)kl + bbase,
                         (const char*)kh + bbase};

  f32x4 acc[4][4];
#pragma unroll
  for (int i = 0; i < 4; i++)
#pragma unroll
    for (int j = 0; j < 4; j++) acc[i][j] = (f32x4){0.f, 0.f, 0.f, 0.f};

  // fragment-read swizzled slot offsets (row&7 == lane&7 for all our rows)
  const int sw0 = ((g4) ^ (lane & 7)) << 4;
  const int sw1 = ((4 + g4) ^ (lane & 7)) << 4;
  int aoff[4], boff[4];
#pragma unroll
  for (int i = 0; i < 4; i++) {
    aoff[i] = (wr * 64 + i * 16 + l15) * 128;
    boff[i] = (wc * 64 + i * 16 + l15) * 128;
  }
  const char* Ab = (const char*)As;
  const char* Bb = (const char*)Bs;

  for (int seg = 0; seg < 3; seg++) {
    const char* A = segA[seg];
    const char* B = segB[seg];
    for (int k0 = 0; k0 < DD * 2; k0 += 128) {  // 64 bf16 per step
#pragma unroll
      for (int p = 0; p < 4; p++) async_copy16(ldsA[p], A + stageOff[p] + k0);
#pragma unroll
      for (int p = 0; p < 4; p++) async_copy16(ldsB[p], B + stageOff[p] + k0);
      __syncthreads();
      {
        bf16x8 af[4], bf[4];
#pragma unroll
        for (int mi = 0; mi < 4; mi++) af[mi] = *(const bf16x8*)(Ab + aoff[mi] + sw0);
#pragma unroll
        for (int ni = 0; ni < 4; ni++) bf[ni] = *(const bf16x8*)(Bb + boff[ni] + sw0);
#pragma unroll
        for (int mi = 0; mi < 4; mi++)
#pragma unroll
          for (int ni = 0; ni < 4; ni++)
            acc[mi][ni] = __builtin_amdgcn_mfma_f32_16x16x32_bf16(af[mi], bf[ni],
                                                                  acc[mi][ni], 0, 0, 0);
#pragma unroll
        for (int mi = 0; mi < 4; mi++) af[mi] = *(const bf16x8*)(Ab + aoff[mi] + sw1);
#pragma unroll
        for (int ni = 0; ni < 4; ni++) bf[ni] = *(const bf16x8*)(Bb + boff[ni] + sw1);
#pragma unroll
        for (int mi = 0; mi < 4; mi++)
#pragma unroll
          for (int ni = 0; ni < 4; ni++)
            acc[mi][ni] = __builtin_amdgcn_mfma_f32_16x16x32_bf16(af[mi], bf[ni],
                                                                  acc[mi][ni], 0, 0, 0);
      }
      __syncthreads();
    }
  }

  // ---- fused diagonal extraction: S[row][row] for tiles tm==tn ----
  // S[tm*128+wr*64+mi*16+(g4*4+rg)][tn*128+wc*64+ni*16+l15] = acc[mi][ni][rg]
  if (tm == tn && wr == wc) {
#pragma unroll
    for (int mi = 0; mi < 4; mi++) {
#pragma unroll
      for (int rg = 0; rg < 4; rg++) {
        if (l15 == g4 * 4 + rg) {
          int row = tm * 128 + wr * 64 + mi * 16 + l15;
          sdiag[b * NN + row] = acc[mi][mi][rg];
        }
      }
    }
  }

  // epilogue: per-row (64 rows per wave) partial max / sumexp over this wave's 64 cols
  float* pmB = pm + ((size_t)(b * 32 + tn * 2 + wc)) * NN + tm * 128 + wr * 64;
  float* plB = pl + ((size_t)(b * 32 + tn * 2 + wc)) * NN + tm * 128 + wr * 64;
#pragma unroll
  for (int mi = 0; mi < 4; mi++) {
#pragma unroll
    for (int r = 0; r < 4; r++) {
      float v0 = acc[mi][0][r], v1 = acc[mi][1][r], v2 = acc[mi][2][r], v3 = acc[mi][3][r];
      float mx = fmaxf(fmaxf(v0, v1), fmaxf(v2, v3));
      mx = fmaxf(mx, __shfl_xor(mx, 1));
      mx = fmaxf(mx, __shfl_xor(mx, 2));
      mx = fmaxf(mx, __shfl_xor(mx, 4));
      mx = fmaxf(mx, __shfl_xor(mx, 8));
      float sm = __expf(v0 - mx) + __expf(v1 - mx) + __expf(v2 - mx) + __expf(v3 - mx);
      sm += __shfl_xor(sm, 1);
      sm += __shfl_xor(sm, 2);
      sm += __shfl_xor(sm, 4);
      sm += __shfl_xor(sm, 8);
      if (l15 == 0) {
        int row = mi * 16 + g4 * 4 + r;
        pmB[row] = mx;
        plB[row] = sm;
      }
    }
  }
}

// ---------------- combine partials + diag softmax ----------------
__global__ __launch_bounds__(256) void k_combine2(const float* __restrict__ pm,
                                                  const float* __restrict__ pl,
                                                  const float* __restrict__ sdiag,
                                                  float* __restrict__ mA,
                                                  float* __restrict__ lA,
                                                  float* __restrict__ dg) {
  int idx = blockIdx.x * 256 + threadIdx.x;  // b*NN + row
  int b = idx >> 11, row = idx & (NN - 1);
  const float* pmb = pm + (size_t)b * 32 * NN + row;
  const float* plb = pl + (size_t)b * 32 * NN + row;
  float m = -INFINITY;
#pragma unroll
  for (int c = 0; c < 32; c++) m = fmaxf(m, pmb[c * NN]);
  float l = 0.f;
#pragma unroll
  for (int c = 0; c < 32; c++) l += plb[c * NN] * __expf(pmb[c * NN] - m);
  mA[idx] = m;
  lA[idx] = l;
  dg[idx] = __expf(sdiag[idx] - m) / l;
}

// ---------------- fallback fp32 row stats ----------------
#define TI 32
#define TJ 128
#define DKK 32

__global__ __launch_bounds__(256) void k_rowstats(const float* __restrict__ q,
                                                  const float* __restrict__ k,
                                                  float* __restrict__ mOut,
                                                  float* __restrict__ lOut) {
  __shared__ float qs[DKK][TI];
  __shared__ float ks[DKK][TJ];
  const int b = blockIdx.y;
  const int r0 = blockIdx.x * TI;
  const int tid = threadIdx.x;
  const int tx = tid & 31;
  const int ty = tid >> 5;
  const float* qb = q + (size_t)b * NN * DD;
  const float* kb = k + (size_t)b * NN * DD;

  float mr[4], lr[4];
#pragma unroll
  for (int i = 0; i < 4; i++) { mr[i] = -INFINITY; lr[i] = 0.f; }

  const int qrow = tid >> 3;
  const int qkk = (tid & 7) * 4;

  for (int c0 = 0; c0 < NN; c0 += TJ) {
    float acc[4][4];
#pragma unroll
    for (int i = 0; i < 4; i++)
#pragma unroll
      for (int j = 0; j < 4; j++) acc[i][j] = 0.f;

    for (int d0 = 0; d0 < DD; d0 += DKK) {
      {
        float4 v = *(const float4*)&qb[(r0 + qrow) * DD + d0 + qkk];
        qs[qkk + 0][qrow] = v.x; qs[qkk + 1][qrow] = v.y;
        qs[qkk + 2][qrow] = v.z; qs[qkk + 3][qrow] = v.w;
      }
#pragma unroll
      for (int p = 0; p < 4; p++) {
        int f = tid + p * 256;
        int col = f >> 3;
        int kk = (f & 7) * 4;
        float4 v = *(const float4*)&kb[(c0 + col) * DD + d0 + kk];
        ks[kk + 0][col] = v.x; ks[kk + 1][col] = v.y;
        ks[kk + 2][col] = v.z; ks[kk + 3][col] = v.w;
      }
      __syncthreads();
#pragma unroll
      for (int kk = 0; kk < DKK; kk++) {
        float4 a = *(const float4*)&qs[kk][ty * 4];
        float4 bb4 = *(const float4*)&ks[kk][tx * 4];
        float av[4] = {a.x, a.y, a.z, a.w};
        float bv[4] = {bb4.x, bb4.y, bb4.z, bb4.w};
#pragma unroll
        for (int i = 0; i < 4; i++)
#pragma unroll
          for (int j = 0; j < 4; j++)
            acc[i][j] = fmaf(av[i], bv[j], acc[i][j]);
      }
      __syncthreads();
    }
#pragma unroll
    for (int i = 0; i < 4; i++) {
      float vmax = fmaxf(fmaxf(acc[i][0], acc[i][1]), fmaxf(acc[i][2], acc[i][3]));
      float nm = fmaxf(mr[i], vmax);
      float s = __expf(acc[i][0] - nm) + __expf(acc[i][1] - nm) +
                __expf(acc[i][2] - nm) + __expf(acc[i][3] - nm);
      lr[i] = lr[i] * __expf(mr[i] - nm) + s;
      mr[i] = nm;
    }
  }
#pragma unroll
  for (int i = 0; i < 4; i++) {
    float m = mr[i], l = lr[i];
    for (int off = 1; off < 32; off <<= 1) {
      float om = __shfl_xor(m, off);
      float ol = __shfl_xor(l, off);
      float nm = fmaxf(m, om);
      l = l * __expf(m - nm) + ol * __expf(om - nm);
      m = nm;
    }
    if (tx == 0) {
      int row = r0 + ty * 4 + i;
      mOut[b * NN + row] = m;
      lOut[b * NN + row] = l;
    }
  }
}

// ---------------- fallback diagonal softmax ----------------
__global__ __launch_bounds__(256) void k_diag(const float* __restrict__ q,
                                              const float* __restrict__ k,
                                              const float* __restrict__ mArr,
                                              const float* __restrict__ lArr,
                                              float* __restrict__ diag) {
  const int b = blockIdx.y;
  const int row = blockIdx.x * 64 + (threadIdx.x >> 2);
  const int part = threadIdx.x & 3;
  const float4* q4 = (const float4*)(q + ((size_t)b * NN + row) * DD);
  const float4* k4 = (const float4*)(k + ((size_t)b * NN + row) * DD);
  float s = 0.f;
  for (int t = part; t < DD / 4; t += 4) {
    float4 a = q4[t], c = k4[t];
    s += a.x * c.x + a.y * c.y + a.z * c.z + a.w * c.w;
  }
  s += __shfl_xor(s, 1);
  s += __shfl_xor(s, 2);
  if (part == 0) {
    int idx = b * NN + row;
    diag[idx] = __expf(s - mArr[idx]) / lArr[idx];
  }
}

// ---------------- per-batch selection ----------------
__global__ __launch_bounds__(256) void k_select(const float* __restrict__ q,
                                                const float* __restrict__ k,
                                                const float* __restrict__ mArr,
                                                const float* __restrict__ lArr,
                                                const float* __restrict__ diag,
                                                int* __restrict__ inst,
                                                int* __restrict__ pairs) {
  const int b = blockIdx.x;
  const int tid = threadIdx.x;
  __shared__ float sd[NN];
  __shared__ float rv[256];
  __shared__ int ri[256];
  __shared__ int schosen[KI];
  __shared__ int sinst[KI];
  __shared__ float srel[KI][KI];

  for (int r = tid; r < NN; r += 256) sd[r] = diag[b * NN + r];
  __syncthreads();

  for (int t = 0; t < KI; t++) {
    float bv = -1e30f;
    int bi = NN;
    for (int r = tid; r < NN; r += 256) {
      float v = sd[r];
      if (v > bv || (v == bv && r < bi)) { bv = v; bi = r; }
    }
    rv[tid] = bv; ri[tid] = bi;
    __syncthreads();
    for (int s = 128; s > 0; s >>= 1) {
      if (tid < s) {
        float ov = rv[tid + s]; int oi = ri[tid + s];
        if (ov > rv[tid] || (ov == rv[tid] && oi < ri[tid])) { rv[tid] = ov; ri[tid] = oi; }
      }
      __syncthreads();
    }
    if (tid == 0) { schosen[t] = ri[0]; sd[ri[0]] = -1.f; }
    __syncthreads();
  }
  if (tid == 0) {
    for (int i = 1; i < KI; i++) {
      int v = schosen[i]; int j = i - 1;
      while (j >= 0 && schosen[j] > v) { schosen[j + 1] = schosen[j]; j--; }
      schosen[j + 1] = v;
    }
    for (int i = 0; i < KI; i++) { sinst[i] = schosen[i]; inst[b * KI + i] = schosen[i]; }
  }
  __syncthreads();

  if (tid < KI * KI) {
    int a = tid / KI, c = tid % KI;
    int ia = sinst[a], ic = sinst[c];
    const float4* qa = (const float4*)(q + ((size_t)b * NN + ia) * DD);
    const float4* kc = (const float4*)(k + ((size_t)b * NN + ic) * DD);
    float s = 0.f;
    for (int t = 0; t < DD / 4; t++) {
      float4 x = qa[t], y = kc[t];
      s += x.x * y.x + x.y * y.y + x.z * y.z + x.w * y.w;
    }
    srel[a][c] = __expf(s - mArr[b * NN + ia]) / lArr[b * NN + ia];
  }
  __syncthreads();

  if (tid < KI) {
    int a = tid;
    float v[KI];
    bool mk[KI];
    for (int c = 0; c < KI; c++) { v[c] = srel[a][c]; mk[c] = false; }
    for (int r = 0; r < KR; r++) {
      float bv = -1e30f; int bi = -1;
      for (int c = 0; c < KI; c++)
        if (!mk[c] && v[c] > bv) { bv = v[c]; bi = c; }
      mk[bi] = true;
    }
    int r = 0;
    for (int c = 0; c < KI; c++)
      if (mk[c]) {
        int p = (b * KI * KR + a * KR + r) * 2;
        pairs[p] = sinst[a];
        pairs[p + 1] = sinst[c];
        r++;
      }
  }
}

// ---------------- gather outputs ----------------
__global__ __launch_bounds__(192) void k_gather(const float* __restrict__ q,
                                                const int* __restrict__ pairs,
                                                float* __restrict__ out) {
  const int p = blockIdx.x;
  const int b = p / (KI * KR);
  const int si = pairs[p * 2];
  const int oi = pairs[p * 2 + 1];
  const int t = threadIdx.x;
  const float4* qs4 = (const float4*)(q + ((size_t)b * NN + si) * DD);
  const float4* qo4 = (const float4*)(q + ((size_t)b * NN + oi) * DD);
  float4 s4 = qs4[t];
  float4 o4 = qo4[t];
  float4* o = (float4*)out;
  const int SEC = BB * KI * KR * DD / 4;
  o[p * (DD / 4) + t] = s4;
  o[SEC + p * (DD / 4) + t] = o4;
  float4 r4;
  r4.x = s4.x + o4.x; r4.y = s4.y + o4.y; r4.z = s4.z + o4.z; r4.w = s4.w + o4.w;
  o[2 * SEC + p * (DD / 4) + t] = r4;
}

extern "C" void kernel_launch(void* const* d_in, const int* in_sizes, int n_in,
                              void* d_out, int out_size, void* d_ws, size_t ws_size,
                              hipStream_t stream) {
  const float* q = (const float*)d_in[0];
  const float* k = (const float*)d_in[1];
  char* ws = (char*)d_ws;

  const size_t S2 = (size_t)BB * NN * DD * 2;  // bytes of one bf16 tensor
  const size_t P = (size_t)BB * 32 * NN * 4;   // partial stats
  const size_t M4 = (size_t)BB * NN * 4;
  const size_t need = 4 * S2 + 2 * P + 4 * M4 + 65536;

  if (ws_size >= need) {
    unsigned short* qh = (unsigned short*)ws;
    unsigned short* ql = (unsigned short*)(ws + S2);
    unsigned short* kh = (unsigned short*)(ws + 2 * S2);
    unsigned short* kl = (unsigned short*)(ws + 3 * S2);
    float* pm = (float*)(ws + 4 * S2);
    float* pl = (float*)(ws + 4 * S2 + P);
    float* sdg = (float*)(ws + 4 * S2 + 2 * P);
    float* mA = sdg + BB * NN;
    float* lA = mA + BB * NN;
    float* dg = lA + BB * NN;
    int* inst = (int*)(dg + BB * NN);
    int* pairs = inst + BB * KI;

    k_split<<<dim3(2048, 2), 256, 0, stream>>>(q, k, qh, ql, kh, kl);
    k_mfma<<<dim3(256, BB), 256, 0, stream>>>(qh, ql, kh, kl, pm, pl, sdg);
    k_combine2<<<BB * NN / 256, 256, 0, stream>>>(pm, pl, sdg, mA, lA, dg);
    k_select<<<BB, 256, 0, stream>>>(q, k, mA, lA, dg, inst, pairs);
    k_gather<<<BB * KI * KR, 192, 0, stream>>>(q, pairs, (float*)d_out);
  } else {
    float* mA = (float*)ws;
    float* lA = mA + BB * NN;
    float* dg = lA + BB * NN;
    int* inst = (int*)(dg + BB * NN);
    int* pairs = inst + BB * KI;

    dim3 g1(NN / TI, BB);
    k_rowstats<<<g1, 256, 0, stream>>>(q, k, mA, lA);
    dim3 g1b(NN / 64, BB);
    k_diag<<<g1b, 256, 0, stream>>>(q, k, mA, lA, dg);
    k_select<<<BB, 256, 0, stream>>>(q, k, mA, lA, dg, inst, pairs);
    k_gather<<<BB * KI * KR, 192, 0, stream>>>(q, pairs, (float*)d_out);
  }
}

// Round 8
// 230.872 us; speedup vs baseline: 1.2441x; 1.0401x over previous
//
#include <hip/hip_runtime.h>

#define BB 8
#define NN 2048
#define DD 768
#define KI 10
#define KR 5

typedef __attribute__((ext_vector_type(8))) short bf16x8;
typedef __attribute__((ext_vector_type(4))) float f32x4;

#define FENCE() asm volatile("" ::: "memory")
#define BARRIER() do { FENCE(); __builtin_amdgcn_s_barrier(); FENCE(); } while (0)
#define VMCNT0() asm volatile("s_waitcnt vmcnt(0)" ::: "memory")

__device__ __forceinline__ void async_copy16(void* ldsp, const void* g) {
  __builtin_amdgcn_global_load_lds(
      (const __attribute__((address_space(1))) unsigned int*)g,
      (__attribute__((address_space(3))) unsigned int*)ldsp, 16, 0, 0);
}

__device__ __forceinline__ unsigned short f2bf_rn(float x) {
  unsigned u = __float_as_uint(x);
  unsigned r = (u + 0x7fffu + ((u >> 16) & 1u)) >> 16;
  return (unsigned short)r;
}

// ---------------- split fp32 -> bf16 hi/lo ----------------
__global__ __launch_bounds__(256) void k_split(const float* __restrict__ q,
                                               const float* __restrict__ k,
                                               unsigned short* __restrict__ qh,
                                               unsigned short* __restrict__ ql,
                                               unsigned short* __restrict__ kh,
                                               unsigned short* __restrict__ kl) {
  const int n4 = BB * NN * DD / 4;
  const float4* src = (const float4*)(blockIdx.y ? k : q);
  ushort4* h = (ushort4*)(blockIdx.y ? kh : qh);
  ushort4* lo = (ushort4*)(blockIdx.y ? kl : ql);
  for (int i = blockIdx.x * blockDim.x + threadIdx.x; i < n4;
       i += gridDim.x * blockDim.x) {
    float4 v = src[i];
    ushort4 hv, lv;
    hv.x = f2bf_rn(v.x); lv.x = f2bf_rn(v.x - __uint_as_float((unsigned)hv.x << 16));
    hv.y = f2bf_rn(v.y); lv.y = f2bf_rn(v.y - __uint_as_float((unsigned)hv.y << 16));
    hv.z = f2bf_rn(v.z); lv.z = f2bf_rn(v.z - __uint_as_float((unsigned)hv.z << 16));
    hv.w = f2bf_rn(v.w); lv.w = f2bf_rn(v.w - __uint_as_float((unsigned)hv.w << 16));
    h[i] = hv; lo[i] = lv;
  }
}

// ---------------- 256x256-tile 8-wave phase-split MFMA kernel ----------------
// 8 waves (2M x 4N), per-wave 128x64 out (acc 128 regs), BK=64, dbuf 128KB LDS,
// XOR slot-swizzle, per-phase barriers + setprio, vmcnt(0) once per K-tile.
#define STAGE_A(u, buf)                                                        \
  do {                                                                         \
    const int uu = (u);                                                        \
    const int ka = (uu < 12 ? uu : uu < 24 ? uu - 12 : uu - 24) * 128;         \
    const char* Ap = (uu < 24 ? (const char*)qh : (const char*)ql) +           \
                     (aScalar + (size_t)ka) + aLane;                           \
    char* d = lds + (buf)*65536 + w * 1024;                                    \
    async_copy16(d, Ap);                                                       \
    async_copy16(d + 8192, Ap + 98304);                                        \
    async_copy16(d + 16384, Ap + 196608);                                      \
    async_copy16(d + 24576, Ap + 294912);                                      \
  } while (0)

#define STAGE_B(u, buf)                                                        \
  do {                                                                         \
    const int uu = (u);                                                        \
    const int kb = (uu < 12 ? uu : uu < 24 ? uu - 12 : uu - 24) * 128;         \
    const char* Bp = ((uu < 12 || uu >= 24) ? (const char*)kh                  \
                                            : (const char*)kl) +               \
                     (bScalar + (size_t)kb) + aLane;                           \
    char* d = lds + (buf)*65536 + 32768 + w * 1024;                            \
    async_copy16(d, Bp);                                                       \
    async_copy16(d + 8192, Bp + 98304);                                        \
    async_copy16(d + 16384, Bp + 196608);                                      \
    async_copy16(d + 24576, Bp + 294912);                                      \
  } while (0)

__global__ __launch_bounds__(512, 2) void k_mfma256(
    const unsigned short* __restrict__ qh, const unsigned short* __restrict__ ql,
    const unsigned short* __restrict__ kh, const unsigned short* __restrict__ kl,
    float* __restrict__ pm, float* __restrict__ pl, float* __restrict__ sdiag) {
  extern __shared__ char lds[];
  const int flat = blockIdx.y * 64 + blockIdx.x;   // 0..511
  const int nid = (flat & 7) * 64 + (flat >> 3);   // one batch per XCD
  const int b = nid >> 6;
  const int tile = nid & 63;
  const int tm = tile >> 3, tn = tile & 7;
  const int tid = threadIdx.x;
  const int lane = tid & 63;
  const int w = __builtin_amdgcn_readfirstlane(tid >> 6);
  const int wr = w >> 2, wc = w & 3;               // 2M x 4N
  const int l15 = lane & 15, g4 = lane >> 4;

  // per-lane staging offset (shared by A and B; rows differ only by scalar base)
  const int aLane = (w * 8 + (lane >> 3)) * 1536 +
                    (((lane & 7) ^ (lane >> 3)) << 4);
  const size_t aScalar = ((size_t)b * NN + (size_t)tm * 256) * 1536;
  const size_t bScalar = ((size_t)b * NN + (size_t)tn * 256) * 1536;

  // fragment read bases (per-lane, immediates step m/n)
  const int swz = (lane & 7);
  const int faB0 = (wr * 128 + l15) * 128 + ((g4 ^ swz) << 4);
  const int faB1 = (wr * 128 + l15) * 128 + (((4 + g4) ^ swz) << 4);
  const int fbB0 = (wc * 64 + l15) * 128 + ((g4 ^ swz) << 4);
  const int fbB1 = (wc * 64 + l15) * 128 + (((4 + g4) ^ swz) << 4);

  f32x4 acc[8][4];
#pragma unroll
  for (int i = 0; i < 8; i++)
#pragma unroll
    for (int j = 0; j < 4; j++) acc[i][j] = (f32x4){0.f, 0.f, 0.f, 0.f};

  // prologue: tile 0 -> buf 0
  STAGE_A(0, 0);
  STAGE_B(0, 0);
  VMCNT0();
  BARRIER();

  for (int t = 0; t < 36; ++t) {
    const int cur = t & 1;
    const char* Ab = lds + cur * 65536;
    const char* Bb = Ab + 32768;
    bf16x8 fa[4][2], fb[2][2];

    // ---- phase 0: stage A(t+1); fa rows 0-3, fb cols 0-1; Q00 ----
    if (t < 35) STAGE_A(t + 1, cur ^ 1);
#pragma unroll
    for (int m = 0; m < 4; m++) {
      fa[m][0] = *(const bf16x8*)(Ab + faB0 + m * 2048);
      fa[m][1] = *(const bf16x8*)(Ab + faB1 + m * 2048);
    }
#pragma unroll
    for (int n = 0; n < 2; n++) {
      fb[n][0] = *(const bf16x8*)(Bb + fbB0 + n * 2048);
      fb[n][1] = *(const bf16x8*)(Bb + fbB1 + n * 2048);
    }
    BARRIER();
    __builtin_amdgcn_s_setprio(1);
#pragma unroll
    for (int m = 0; m < 4; m++)
#pragma unroll
      for (int n = 0; n < 2; n++) {
        acc[m][n] = __builtin_amdgcn_mfma_f32_16x16x32_bf16(fa[m][0], fb[n][0], acc[m][n], 0, 0, 0);
        acc[m][n] = __builtin_amdgcn_mfma_f32_16x16x32_bf16(fa[m][1], fb[n][1], acc[m][n], 0, 0, 0);
      }
    __builtin_amdgcn_s_setprio(0);
    BARRIER();

    // ---- phase 1: stage B(t+1); fb cols 2-3; Q01 (fa carried) ----
    if (t < 35) STAGE_B(t + 1, cur ^ 1);
#pragma unroll
    for (int n = 0; n < 2; n++) {
      fb[n][0] = *(const bf16x8*)(Bb + fbB0 + (n + 2) * 2048);
      fb[n][1] = *(const bf16x8*)(Bb + fbB1 + (n + 2) * 2048);
    }
    BARRIER();
    __builtin_amdgcn_s_setprio(1);
#pragma unroll
    for (int m = 0; m < 4; m++)
#pragma unroll
      for (int n = 0; n < 2; n++) {
        acc[m][n + 2] = __builtin_amdgcn_mfma_f32_16x16x32_bf16(fa[m][0], fb[n][0], acc[m][n + 2], 0, 0, 0);
        acc[m][n + 2] = __builtin_amdgcn_mfma_f32_16x16x32_bf16(fa[m][1], fb[n][1], acc[m][n + 2], 0, 0, 0);
      }
    __builtin_amdgcn_s_setprio(0);
    BARRIER();

    // ---- phase 2: fa rows 4-7; Q11 (fb carried) ----
#pragma unroll
    for (int m = 0; m < 4; m++) {
      fa[m][0] = *(const bf16x8*)(Ab + faB0 + (m + 4) * 2048);
      fa[m][1] = *(const bf16x8*)(Ab + faB1 + (m + 4) * 2048);
    }
    BARRIER();
    __builtin_amdgcn_s_setprio(1);
#pragma unroll
    for (int m = 0; m < 4; m++)
#pragma unroll
      for (int n = 0; n < 2; n++) {
        acc[m + 4][n + 2] = __builtin_amdgcn_mfma_f32_16x16x32_bf16(fa[m][0], fb[n][0], acc[m + 4][n + 2], 0, 0, 0);
        acc[m + 4][n + 2] = __builtin_amdgcn_mfma_f32_16x16x32_bf16(fa[m][1], fb[n][1], acc[m + 4][n + 2], 0, 0, 0);
      }
    __builtin_amdgcn_s_setprio(0);
    BARRIER();

    // ---- phase 3: fb cols 0-1; Q10; drain ----
#pragma unroll
    for (int n = 0; n < 2; n++) {
      fb[n][0] = *(const bf16x8*)(Bb + fbB0 + n * 2048);
      fb[n][1] = *(const bf16x8*)(Bb + fbB1 + n * 2048);
    }
    BARRIER();
    __builtin_amdgcn_s_setprio(1);
#pragma unroll
    for (int m = 0; m < 4; m++)
#pragma unroll
      for (int n = 0; n < 2; n++) {
        acc[m + 4][n] = __builtin_amdgcn_mfma_f32_16x16x32_bf16(fa[m][0], fb[n][0], acc[m + 4][n], 0, 0, 0);
        acc[m + 4][n] = __builtin_amdgcn_mfma_f32_16x16x32_bf16(fa[m][1], fb[n][1], acc[m + 4][n], 0, 0, 0);
      }
    __builtin_amdgcn_s_setprio(0);
    VMCNT0();
    BARRIER();
  }

  // ---- diagonal extraction (tiles tm==tn; verified in r5/r6) ----
  if (tm == tn && (wc >> 1) == wr) {
#pragma unroll
    for (int n = 0; n < 4; n++) {
      const int m = (wc & 1) * 4 + n;
#pragma unroll
      for (int rg = 0; rg < 4; rg++) {
        if (l15 == g4 * 4 + rg) {
          const int row = tm * 256 + wr * 128 + m * 16 + l15;
          sdiag[b * NN + row] = acc[m][n][rg];
        }
      }
    }
  }

  // ---- per-row partial max / sumexp over this wave's 64 cols ----
  float* pmB = pm + ((size_t)(b * 32 + tn * 4 + wc)) * NN + tm * 256 + wr * 128;
  float* plB = pl + ((size_t)(b * 32 + tn * 4 + wc)) * NN + tm * 256 + wr * 128;
#pragma unroll
  for (int m = 0; m < 8; m++) {
#pragma unroll
    for (int rg = 0; rg < 4; rg++) {
      float v0 = acc[m][0][rg], v1 = acc[m][1][rg], v2 = acc[m][2][rg], v3 = acc[m][3][rg];
      float mx = fmaxf(fmaxf(v0, v1), fmaxf(v2, v3));
      mx = fmaxf(mx, __shfl_xor(mx, 1));
      mx = fmaxf(mx, __shfl_xor(mx, 2));
      mx = fmaxf(mx, __shfl_xor(mx, 4));
      mx = fmaxf(mx, __shfl_xor(mx, 8));
      float sm = __expf(v0 - mx) + __expf(v1 - mx) + __expf(v2 - mx) + __expf(v3 - mx);
      sm += __shfl_xor(sm, 1);
      sm += __shfl_xor(sm, 2);
      sm += __shfl_xor(sm, 4);
      sm += __shfl_xor(sm, 8);
      if (l15 == 0) {
        pmB[m * 16 + g4 * 4 + rg] = mx;
        plB[m * 16 + g4 * 4 + rg] = sm;
      }
    }
  }
}

// ---------------- proven 128x128 MFMA kernel (r7 fallback) ----------------
__global__ __launch_bounds__(256, 4) void k_mfma(const unsigned short* __restrict__ qh,
                                                 const unsigned short* __restrict__ ql,
                                                 const unsigned short* __restrict__ kh,
                                                 const unsigned short* __restrict__ kl,
                                                 float* __restrict__ pm,
                                                 float* __restrict__ pl,
                                                 float* __restrict__ sdiag) {
  __shared__ short As[128 * 64];
  __shared__ short Bs[128 * 64];
  const int flat = blockIdx.y * 256 + blockIdx.x;
  const int nid = (flat & 7) * 256 + (flat >> 3);
  const int b = nid >> 8;
  const int tile = nid & 255;
  const int tm = tile >> 4;
  const int tn = tile & 15;
  const int tid = threadIdx.x;
  const int w = tid >> 6, lane = tid & 63;
  const int wr = w >> 1, wc = w & 1;
  const int l15 = lane & 15, g4 = lane >> 4;

  int stageOff[4];
  char* ldsA[4];
  char* ldsB[4];
#pragma unroll
  for (int p = 0; p < 4; p++) {
    int L = w * 4096 + p * 1024 + lane * 16;
    int row = L >> 7;
    int s = (L >> 4) & 7;
    stageOff[p] = row * (DD * 2) + ((s ^ (row & 7)) << 4);
    ldsA[p] = (char*)As + w * 4096 + p * 1024;
    ldsB[p] = (char*)Bs + w * 4096 + p * 1024;
  }
  const size_t abase = ((size_t)b * NN + (size_t)tm * 128) * (DD * 2);
  const size_t bbase = ((size_t)b * NN + (size_t)tn * 128) * (DD * 2);
  const char* segA[3] = {(const char*)qh + abase, (const char*)qh + abase,
                         (const char*)ql + abase};
  const char* segB[3] = {(const char*)kh + bbase, (const char*)kl + bbase,
                         (const char*)kh + bbase};

  f32x4 acc[4][4];
#pragma unroll
  for (int i = 0; i < 4; i++)
#pragma unroll
    for (int j = 0; j < 4; j++) acc[i][j] = (f32x4){0.f, 0.f, 0.f, 0.f};

  const int sw0 = ((g4) ^ (lane & 7)) << 4;
  const int sw1 = ((4 + g4) ^ (lane & 7)) << 4;
  int aoff[4], boff[4];
#pragma unroll
  for (int i = 0; i < 4; i++) {
    aoff[i] = (wr * 64 + i * 16 + l15) * 128;
    boff[i] = (wc * 64 + i * 16 + l15) * 128;
  }
  const char* Ab = (const char*)As;
  const char* Bb = (const char*)Bs;

  for (int seg = 0; seg < 3; seg++) {
    const char* A = segA[seg];
    const char* B = segB[seg];
    for (int k0 = 0; k0 < DD * 2; k0 += 128) {
#pragma unroll
      for (int p = 0; p < 4; p++) async_copy16(ldsA[p], A + stageOff[p] + k0);
#pragma unroll
      for (int p = 0; p < 4; p++) async_copy16(ldsB[p], B + stageOff[p] + k0);
      __syncthreads();
      {
        bf16x8 af[4], bf[4];
#pragma unroll
        for (int mi = 0; mi < 4; mi++) af[mi] = *(const bf16x8*)(Ab + aoff[mi] + sw0);
#pragma unroll
        for (int ni = 0; ni < 4; ni++) bf[ni] = *(const bf16x8*)(Bb + boff[ni] + sw0);
#pragma unroll
        for (int mi = 0; mi < 4; mi++)
#pragma unroll
          for (int ni = 0; ni < 4; ni++)
            acc[mi][ni] = __builtin_amdgcn_mfma_f32_16x16x32_bf16(af[mi], bf[ni],
                                                                  acc[mi][ni], 0, 0, 0);
#pragma unroll
        for (int mi = 0; mi < 4; mi++) af[mi] = *(const bf16x8*)(Ab + aoff[mi] + sw1);
#pragma unroll
        for (int ni = 0; ni < 4; ni++) bf[ni] = *(const bf16x8*)(Bb + boff[ni] + sw1);
#pragma unroll
        for (int mi = 0; mi < 4; mi++)
#pragma unroll
          for (int ni = 0; ni < 4; ni++)
            acc[mi][ni] = __builtin_amdgcn_mfma_f32_16x16x32_bf16(af[mi], bf[ni],
                                                                  acc[mi][ni], 0, 0, 0);
      }
      __syncthreads();
    }
  }

  if (tm == tn && wr == wc) {
#pragma unroll
    for (int mi = 0; mi < 4; mi++) {
#pragma unroll
      for (int rg = 0; rg < 4; rg++) {
        if (l15 == g4 * 4 + rg) {
          int row = tm * 128 + wr * 64 + mi * 16 + l15;
          sdiag[b * NN + row] = acc[mi][mi][rg];
        }
      }
    }
  }

  float* pmB = pm + ((size_t)(b * 32 + tn * 2 + wc)) * NN + tm * 128 + wr * 64;
  float* plB = pl + ((size_t)(b * 32 + tn * 2 + wc)) * NN + tm * 128 + wr * 64;
#pragma unroll
  for (int mi = 0; mi < 4; mi++) {
#pragma unroll
    for (int r = 0; r < 4; r++) {
      float v0 = acc[mi][0][r], v1 = acc[mi][1][r], v2 = acc[mi][2][r], v3 = acc[mi][3][r];
      float mx = fmaxf(fmaxf(v0, v1), fmaxf(v2, v3));
      mx = fmaxf(mx, __shfl_xor(mx, 1));
      mx = fmaxf(mx, __shfl_xor(mx, 2));
      mx = fmaxf(mx, __shfl_xor(mx, 4));
      mx = fmaxf(mx, __shfl_xor(mx, 8));
      float sm = __expf(v0 - mx) + __expf(v1 - mx) + __expf(v2 - mx) + __expf(v3 - mx);
      sm += __shfl_xor(sm, 1);
      sm += __shfl_xor(sm, 2);
      sm += __shfl_xor(sm, 4);
      sm += __shfl_xor(sm, 8);
      if (l15 == 0) {
        int row = mi * 16 + g4 * 4 + r;
        pmB[row] = mx;
        plB[row] = sm;
      }
    }
  }
}

// ---------------- combine partials + diag softmax ----------------
__global__ __launch_bounds__(256) void k_combine2(const float* __restrict__ pm,
                                                  const float* __restrict__ pl,
                                                  const float* __restrict__ sdiag,
                                                  float* __restrict__ mA,
                                                  float* __restrict__ lA,
                                                  float* __restrict__ dg) {
  int idx = blockIdx.x * 256 + threadIdx.x;
  int b = idx >> 11, row = idx & (NN - 1);
  const float* pmb = pm + (size_t)b * 32 * NN + row;
  const float* plb = pl + (size_t)b * 32 * NN + row;
  float m = -INFINITY;
#pragma unroll
  for (int c = 0; c < 32; c++) m = fmaxf(m, pmb[c * NN]);
  float l = 0.f;
#pragma unroll
  for (int c = 0; c < 32; c++) l += plb[c * NN] * __expf(pmb[c * NN] - m);
  mA[idx] = m;
  lA[idx] = l;
  dg[idx] = __expf(sdiag[idx] - m) / l;
}

// ---------------- fallback fp32 row stats ----------------
#define TI 32
#define TJ 128
#define DKK 32

__global__ __launch_bounds__(256) void k_rowstats(const float* __restrict__ q,
                                                  const float* __restrict__ k,
                                                  float* __restrict__ mOut,
                                                  float* __restrict__ lOut) {
  __shared__ float qs[DKK][TI];
  __shared__ float ks[DKK][TJ];
  const int b = blockIdx.y;
  const int r0 = blockIdx.x * TI;
  const int tid = threadIdx.x;
  const int tx = tid & 31;
  const int ty = tid >> 5;
  const float* qb = q + (size_t)b * NN * DD;
  const float* kb = k + (size_t)b * NN * DD;

  float mr[4], lr[4];
#pragma unroll
  for (int i = 0; i < 4; i++) { mr[i] = -INFINITY; lr[i] = 0.f; }

  const int qrow = tid >> 3;
  const int qkk = (tid & 7) * 4;

  for (int c0 = 0; c0 < NN; c0 += TJ) {
    float acc[4][4];
#pragma unroll
    for (int i = 0; i < 4; i++)
#pragma unroll
      for (int j = 0; j < 4; j++) acc[i][j] = 0.f;

    for (int d0 = 0; d0 < DD; d0 += DKK) {
      {
        float4 v = *(const float4*)&qb[(r0 + qrow) * DD + d0 + qkk];
        qs[qkk + 0][qrow] = v.x; qs[qkk + 1][qrow] = v.y;
        qs[qkk + 2][qrow] = v.z; qs[qkk + 3][qrow] = v.w;
      }
#pragma unroll
      for (int p = 0; p < 4; p++) {
        int f = tid + p * 256;
        int col = f >> 3;
        int kk = (f & 7) * 4;
        float4 v = *(const float4*)&kb[(c0 + col) * DD + d0 + kk];
        ks[kk + 0][col] = v.x; ks[kk + 1][col] = v.y;
        ks[kk + 2][col] = v.z; ks[kk + 3][col] = v.w;
      }
      __syncthreads();
#pragma unroll
      for (int kk = 0; kk < DKK; kk++) {
        float4 a = *(const float4*)&qs[kk][ty * 4];
        float4 bb4 = *(const float4*)&ks[kk][tx * 4];
        float av[4] = {a.x, a.y, a.z, a.w};
        float bv[4] = {bb4.x, bb4.y, bb4.z, bb4.w};
#pragma unroll
        for (int i = 0; i < 4; i++)
#pragma unroll
          for (int j = 0; j < 4; j++)
            acc[i][j] = fmaf(av[i], bv[j], acc[i][j]);
      }
      __syncthreads();
    }
#pragma unroll
    for (int i = 0; i < 4; i++) {
      float vmax = fmaxf(fmaxf(acc[i][0], acc[i][1]), fmaxf(acc[i][2], acc[i][3]));
      float nm = fmaxf(mr[i], vmax);
      float s = __expf(acc[i][0] - nm) + __expf(acc[i][1] - nm) +
                __expf(acc[i][2] - nm) + __expf(acc[i][3] - nm);
      lr[i] = lr[i] * __expf(mr[i] - nm) + s;
      mr[i] = nm;
    }
  }
#pragma unroll
  for (int i = 0; i < 4; i++) {
    float m = mr[i], l = lr[i];
    for (int off = 1; off < 32; off <<= 1) {
      float om = __shfl_xor(m, off);
      float ol = __shfl_xor(l, off);
      float nm = fmaxf(m, om);
      l = l * __expf(m - nm) + ol * __expf(om - nm);
      m = nm;
    }
    if (tx == 0) {
      int row = r0 + ty * 4 + i;
      mOut[b * NN + row] = m;
      lOut[b * NN + row] = l;
    }
  }
}

// ---------------- fallback diagonal softmax ----------------
__global__ __launch_bounds__(256) void k_diag(const float* __restrict__ q,
                                              const float* __restrict__ k,
                                              const float* __restrict__ mArr,
                                              const float* __restrict__ lArr,
                                              float* __restrict__ diag) {
  const int b = blockIdx.y;
  const int row = blockIdx.x * 64 + (threadIdx.x >> 2);
  const int part = threadIdx.x & 3;
  const float4* q4 = (const float4*)(q + ((size_t)b * NN + row) * DD);
  const float4* k4 = (const float4*)(k + ((size_t)b * NN + row) * DD);
  float s = 0.f;
  for (int t = part; t < DD / 4; t += 4) {
    float4 a = q4[t], c = k4[t];
    s += a.x * c.x + a.y * c.y + a.z * c.z + a.w * c.w;
  }
  s += __shfl_xor(s, 1);
  s += __shfl_xor(s, 2);
  if (part == 0) {
    int idx = b * NN + row;
    diag[idx] = __expf(s - mArr[idx]) / lArr[idx];
  }
}

// ---------------- per-batch selection (register-resident top-10) ----------------
__global__ __launch_bounds__(256) void k_select(const float* __restrict__ q,
                                                const float* __restrict__ k,
                                                const float* __restrict__ mArr,
                                                const float* __restrict__ lArr,
                                                const float* __restrict__ diag,
                                                int* __restrict__ inst,
                                                int* __restrict__ pairs) {
  const int b = blockIdx.x;
  const int tid = threadIdx.x;
  __shared__ float rv[256];
  __shared__ int ri[256];
  __shared__ int schosen[KI];
  __shared__ int sinst[KI];
  __shared__ float srel[KI][KI];

  float v[8];
#pragma unroll
  for (int j = 0; j < 8; j++) v[j] = diag[b * NN + j * 256 + tid];

  for (int t = 0; t < KI; t++) {
    float bv = -1e30f;
    int bj = 0;
#pragma unroll
    for (int j = 0; j < 8; j++)
      if (v[j] > bv) { bv = v[j]; bj = j; }
    rv[tid] = bv;
    ri[tid] = bj * 256 + tid;
    __syncthreads();
    for (int s = 128; s > 0; s >>= 1) {
      if (tid < s) {
        float ov = rv[tid + s]; int oi = ri[tid + s];
        if (ov > rv[tid] || (ov == rv[tid] && oi < ri[tid])) { rv[tid] = ov; ri[tid] = oi; }
      }
      __syncthreads();
    }
    const int win = ri[0];
    if (tid == 0) schosen[t] = win;
    if (tid == (win & 255)) {
      const int jj = win >> 8;
#pragma unroll
      for (int j = 0; j < 8; j++)
        if (j == jj) v[j] = -1e30f;
    }
    __syncthreads();
  }
  if (tid == 0) {
    for (int i = 1; i < KI; i++) {
      int vv = schosen[i]; int j = i - 1;
      while (j >= 0 && schosen[j] > vv) { schosen[j + 1] = schosen[j]; j--; }
      schosen[j + 1] = vv;
    }
    for (int i = 0; i < KI; i++) { sinst[i] = schosen[i]; inst[b * KI + i] = schosen[i]; }
  }
  __syncthreads();

  if (tid < KI * KI) {
    int a = tid / KI, c = tid % KI;
    int ia = sinst[a], ic = sinst[c];
    const float4* qa = (const float4*)(q + ((size_t)b * NN + ia) * DD);
    const float4* kc = (const float4*)(k + ((size_t)b * NN + ic) * DD);
    float s = 0.f;
    for (int t = 0; t < DD / 4; t++) {
      float4 x = qa[t], y = kc[t];
      s += x.x * y.x + x.y * y.y + x.z * y.z + x.w * y.w;
    }
    srel[a][c] = __expf(s - mArr[b * NN + ia]) / lArr[b * NN + ia];
  }
  __syncthreads();

  if (tid < KI) {
    int a = tid;
    float vv[KI];
    bool mk[KI];
    for (int c = 0; c < KI; c++) { vv[c] = srel[a][c]; mk[c] = false; }
    for (int r = 0; r < KR; r++) {
      float bv = -1e30f; int bi = -1;
      for (int c = 0; c < KI; c++)
        if (!mk[c] && vv[c] > bv) { bv = vv[c]; bi = c; }
      mk[bi] = true;
    }
    int r = 0;
    for (int c = 0; c < KI; c++)
      if (mk[c]) {
        int p = (b * KI * KR + a * KR + r) * 2;
        pairs[p] = sinst[a];
        pairs[p + 1] = sinst[c];
        r++;
      }
  }
}

// ---------------- gather outputs ----------------
__global__ __launch_bounds__(192) void k_gather(const float* __restrict__ q,
                                                const int* __restrict__ pairs,
                                                float* __restrict__ out) {
  const int p = blockIdx.x;
  const int b = p / (KI * KR);
  const int si = pairs[p * 2];
  const int oi = pairs[p * 2 + 1];
  const int t = threadIdx.x;
  const float4* qs4 = (const float4*)(q + ((size_t)b * NN + si) * DD);
  const float4* qo4 = (const float4*)(q + ((size_t)b * NN + oi) * DD);
  float4 s4 = qs4[t];
  float4 o4 = qo4[t];
  float4* o = (float4*)out;
  const int SEC = BB * KI * KR * DD / 4;
  o[p * (DD / 4) + t] = s4;
  o[SEC + p * (DD / 4) + t] = o4;
  float4 r4;
  r4.x = s4.x + o4.x; r4.y = s4.y + o4.y; r4.z = s4.z + o4.z; r4.w = s4.w + o4.w;
  o[2 * SEC + p * (DD / 4) + t] = r4;
}

extern "C" void kernel_launch(void* const* d_in, const int* in_sizes, int n_in,
                              void* d_out, int out_size, void* d_ws, size_t ws_size,
                              hipStream_t stream) {
  const float* q = (const float*)d_in[0];
  const float* k = (const float*)d_in[1];
  char* ws = (char*)d_ws;

  const size_t S2 = (size_t)BB * NN * DD * 2;
  const size_t P = (size_t)BB * 32 * NN * 4;
  const size_t M4 = (size_t)BB * NN * 4;
  const size_t need = 4 * S2 + 2 * P + 4 * M4 + 65536;

  if (ws_size >= need) {
    unsigned short* qh = (unsigned short*)ws;
    unsigned short* ql = (unsigned short*)(ws + S2);
    unsigned short* kh = (unsigned short*)(ws + 2 * S2);
    unsigned short* kl = (unsigned short*)(ws + 3 * S2);
    float* pm = (float*)(ws + 4 * S2);
    float* pl = (float*)(ws + 4 * S2 + P);
    float* sdg = (float*)(ws + 4 * S2 + 2 * P);
    float* mA = sdg + BB * NN;
    float* lA = mA + BB * NN;
    float* dg = lA + BB * NN;
    int* inst = (int*)(dg + BB * NN);
    int* pairs = inst + BB * KI;

    k_split<<<dim3(2048, 2), 256, 0, stream>>>(q, k, qh, ql, kh, kl);

    // spill check: use the 256^2 8-wave kernel only if it compiled scratch-free
    hipFuncAttributes fattr;
    bool fast = (hipFuncGetAttributes(&fattr, (const void*)k_mfma256) == hipSuccess) &&
                (fattr.localSizeBytes <= 64);
    if (fast) {
      (void)hipFuncSetAttribute((const void*)k_mfma256,
                                hipFuncAttributeMaxDynamicSharedMemorySize, 131072);
      k_mfma256<<<dim3(64, BB), 512, 131072, stream>>>(qh, ql, kh, kl, pm, pl, sdg);
    } else {
      k_mfma<<<dim3(256, BB), 256, 0, stream>>>(qh, ql, kh, kl, pm, pl, sdg);
    }
    k_combine2<<<BB * NN / 256, 256, 0, stream>>>(pm, pl, sdg, mA, lA, dg);
    k_select<<<BB, 256, 0, stream>>>(q, k, mA, lA, dg, inst, pairs);
    k_gather<<<BB * KI * KR, 192, 0, stream>>>(q, pairs, (float*)d_out);
  } else {
    float* mA = (float*)ws;
    float* lA = mA + BB * NN;
    float* dg = lA + BB * NN;
    int* inst = (int*)(dg + BB * NN);
    int* pairs = inst + BB * KI;

    dim3 g1(NN / TI, BB);
    k_rowstats<<<g1, 256, 0, stream>>>(q, k, mA, lA);
    dim3 g1b(NN / 64, BB);
    k_diag<<<g1b, 256, 0, stream>>>(q, k, mA, lA, dg);
    k_select<<<BB, 256, 0, stream>>>(q, k, mA, lA, dg, inst, pairs);
    k_gather<<<BB * KI * KR, 192, 0, stream>>>(q, pairs, (float*)d_out);
  }
}